// Round 11
// baseline (632.576 us; speedup 1.0000x reference)
//
#include <hip/hip_runtime.h>
#include <hip/hip_bf16.h>
#include <math.h>

#define B 8
#define T_MEL 400
#define N_MEL 80
#define L_TXT 128
#define D_TXT 512
#define E 256
#define HID 256
#define EMB 128
#define N_SPK 100
#define HH 128

// ---- workspace layout (float element offsets) ----
#define OFF_W      0
#define OFF_C      256
#define OFF_WXT    272
#define OFF_WQT    (OFF_WXT + N_MEL*E)        // 20752
#define OFF_WIHT   (OFF_WQT + D_TXT*E)        // 151824
#define OFF_BSUM   (OFF_WIHT + 2*2*256*512)   // 676112
#define OFF_X1     (OFF_BSUM + 2048)          // 678160
#define OFF_Q1     (OFF_X1 + B*T_MEL*E)       // 1497360
#define OFF_G      OFF_X1                      // gates overlay x1+q1 (dead by then)
#define OFF_H0     (OFF_Q1 + B*L_TXT*E)       // 1759504
#define OFF_O1     (OFF_H0 + B*L_TXT*E)       // 2021648
#define OFF_HS0    OFF_H0                      // hseq layer0 overlays H0 (dead after k_gates0)
#define OFF_HS1    OFF_O1                      // hseq layer1 in O1 region

typedef _Float16 half2v __attribute__((ext_vector_type(2)));

__device__ __forceinline__ float fast_sigmoid(float x){ return 1.f/(1.f+__expf(-x)); }
__device__ __forceinline__ float fast_tanh(float x){ float e=__expf(2.f*x); return 1.f - 2.f/(e+1.f); }

__device__ __forceinline__ float fdot2(uint a, uint b, float c){
  half2v ha = __builtin_bit_cast(half2v, a);
  half2v hb = __builtin_bit_cast(half2v, b);
#if __has_builtin(__builtin_amdgcn_fdot2)
  return __builtin_amdgcn_fdot2(ha, hb, c, false);
#else
  float r;
  asm("v_dot2_f32_f16 %0, %1, %2, %3" : "=v"(r) : "v"(a), "v"(b), "v"(c));
  return r;
#endif
}
__device__ __forceinline__ uint packh2(float a, float b){
  union { _Float16 h[2]; uint u; } x;
  x.h[0] = (_Float16)a; x.h[1] = (_Float16)b; return x.u;
}

// ---- prep: w = Wout^T v, c = bout.v ; transposes WxT, WqT, WihT ; bias sums ----
// MUST be its own kernel: k_xq's blocks consume WXT/WQT (no intra-kernel ordering).
__global__ __launch_bounds__(256) void k_prep(const float* __restrict__ Wout, const float* __restrict__ bout,
                       const float* __restrict__ v,    const float* __restrict__ Wx,
                       const float* __restrict__ Wq,   const float* __restrict__ wih,
                       const float* __restrict__ bih,  const float* __restrict__ bhh,
                       float* __restrict__ ws){
  int blk = blockIdx.x, tid = threadIdx.x;
  if (blk == 0){
    float acc = 0.f;
    for (int j=0;j<E;j++) acc += Wout[j*E + tid] * v[j];
    ws[OFF_W + tid] = acc;
    if (tid==0){ float c=0.f; for(int j=0;j<E;j++) c += bout[j]*v[j]; ws[OFF_C]=c; }
  } else if (blk <= N_MEL){
    int m = blk-1;
    ws[OFF_WXT + m*E + tid] = Wx[tid*N_MEL + m];
  } else if (blk <= N_MEL + D_TXT){
    int k = blk-1-N_MEL;
    ws[OFF_WQT + k*E + tid] = Wq[tid*D_TXT + k];
  } else if (blk <= N_MEL + D_TXT + 1024){
    int idx = blk-1-N_MEL-D_TXT;      // ld*256 + k
    int ld = idx >> 8, k = idx & 255;
    for (int g = tid; g < 512; g += 256)
      ws[OFF_WIHT + idx*512 + g] = wih[(ld*512+g)*256 + k];
  } else {
    for (int i = tid; i < 2048; i += 256)
      ws[OFF_BSUM + i] = bih[i] + bhh[i];
  }
}

// ---- x1 (blk<800) | q1 (blk 800..1055) ; reads WXT/WQT written by k_prep ----
__global__ __launch_bounds__(256) void k_xq(const float* __restrict__ x,    const float* __restrict__ bx,
                                            const float* __restrict__ text, const float* __restrict__ bq,
                                            float* __restrict__ ws){
  __shared__ float sbuf[2048];
  int blk = blockIdx.x, tid = threadIdx.x;
  if (blk < 800){
    int b = blk/100; int t0 = (blk%100)*4;
    float (*sx)[4] = (float(*)[4])sbuf;
    for (int i = tid; i < N_MEL*4; i += 256){
      int m = i>>2, ii = i&3;
      sx[m][ii] = x[(b*N_MEL+m)*T_MEL + t0 + ii];
    }
    __syncthreads();
    float bxe = bx[tid];
    float a0=bxe,a1=bxe,a2=bxe,a3=bxe;
    const float* wxt = ws + OFF_WXT;
    #pragma unroll 4
    for (int m=0;m<N_MEL;m++){
      float w = wxt[m*E + tid];
      a0 += sx[m][0]*w; a1 += sx[m][1]*w; a2 += sx[m][2]*w; a3 += sx[m][3]*w;
    }
    float* x1 = ws + OFF_X1 + (b*T_MEL + t0)*E + tid;
    x1[0]=a0; x1[E]=a1; x1[2*E]=a2; x1[3*E]=a3;
  } else {
    int bb = blk - 800;
    int b = bb/32; int l0 = (bb%32)*4;
    float (*st)[D_TXT] = (float(*)[D_TXT])sbuf;
    for (int i = tid; i < 4*D_TXT; i += 256){
      int li = i / D_TXT, k = i % D_TXT;
      st[li][k] = text[(b*L_TXT + l0 + li)*D_TXT + k];
    }
    __syncthreads();
    float bqe = bq[tid];
    float a0=bqe,a1=bqe,a2=bqe,a3=bqe;
    const float* wqt = ws + OFF_WQT;
    #pragma unroll 2
    for (int k=0;k<D_TXT;k++){
      float w = wqt[k*E + tid];
      a0 += st[0][k]*w; a1 += st[1][k]*w; a2 += st[2][k]*w; a3 += st[3][k]*w;
    }
    float* q1 = ws + OFF_Q1 + (b*L_TXT + l0)*E + tid;
    q1[0]=a0; q1[E]=a1; q1[2*E]=a2; q1[3*E]=a3;
  }
}

// ---- scores + masked softmax + context + h0 ; one block per (b,l) ----
__global__ __launch_bounds__(256) void k_score(const int* __restrict__ mel_len,
                                               float* __restrict__ ws,
                                               float* __restrict__ d_out){
  int blk = blockIdx.x; int b = blk >> 7; int l = blk & 127;
  int tid = threadIdx.x; int lane = tid & 63; int wv = tid >> 6;
  __shared__ float sl[T_MEL];
  __shared__ float red[8];
  const float* x1 = ws + OFF_X1 + b*T_MEL*E;
  const float* q1 = ws + OFF_Q1 + (b*L_TXT+l)*E;
  float qv[4], wv4[4];
  #pragma unroll
  for (int j=0;j<4;j++){ qv[j] = q1[lane+64*j]; wv4[j] = ws[OFF_W + lane + 64*j]; }
  float cc = ws[OFF_C];
  int len = mel_len[b];
  for (int t = wv; t < T_MEL; t += 4){
    const float* xr = x1 + t*E;
    float s = 0.f;
    #pragma unroll
    for (int j=0;j<4;j++) s += wv4[j]*fast_tanh(xr[lane+64*j] + qv[j]);
    #pragma unroll
    for (int off=32; off>=1; off>>=1) s += __shfl_xor(s, off);
    if (lane==0) sl[t] = s + cc;
  }
  __syncthreads();
  float mx = -3.0e38f;
  for (int t = tid; t < T_MEL; t += 256) if (t < len) mx = fmaxf(mx, sl[t]);
  #pragma unroll
  for (int off=32; off>=1; off>>=1) mx = fmaxf(mx, __shfl_xor(mx, off));
  if (lane==0) red[wv] = mx;
  __syncthreads();
  mx = fmaxf(fmaxf(red[0],red[1]),fmaxf(red[2],red[3]));
  float se = 0.f;
  for (int t = tid; t < T_MEL; t += 256){
    float p = (t < len) ? __expf(sl[t]-mx) : 0.f;
    sl[t] = p; se += p;
  }
  #pragma unroll
  for (int off=32; off>=1; off>>=1) se += __shfl_xor(se, off);
  if (lane==0) red[4+wv] = se;
  __syncthreads();
  float rsum = 1.f/(red[4]+red[5]+red[6]+red[7]);
  float* sc_out = d_out + 1824 + (b*L_TXT + l)*T_MEL;
  for (int t = tid; t < T_MEL; t += 256){
    float p = sl[t]*rsum;
    sl[t] = p; sc_out[t] = p;
  }
  __syncthreads();
  float a = 0.f;
  int e = tid;
  #pragma unroll 4
  for (int t = 0; t < len; t++) a += sl[t]*x1[t*E + e];
  ws[OFF_H0 + (b*L_TXT+l)*E + e] = q1[e] + a;
}

// ---- gates: in @ WihT + (bih+bhh) ; layer0 reads H0[b][l][256];
//      layer1 reads hseq0[d][b][u][s] with pack-reverse fold composed in.
//      output: G[dir][t][b][unit*4 + gate]  (gate 0:i 1:f 2:g 3:o) ----
__global__ __launch_bounds__(512) void k_gates(const float* __restrict__ in,
                                               const float* __restrict__ hs,
                                               const int* __restrict__ txt_len,
                                               float* __restrict__ gates, int layer,
                                               float* __restrict__ ws){
  int idx = blockIdx.x; int tt = idx & 15; int dir = (idx>>4)&1; int b = idx>>5;
  int tid = threadIdx.x;
  __shared__ float si[8][HID];
  int len = txt_len[b];
  for (int i = tid; i < 8*HID; i += 512){
    int r = i >> 8, k = i & 255;
    int t = tt*8 + r;
    int row = dir ? max(0, len-1-t) : t;
    if (layer == 0){
      si[r][k] = in[(b*L_TXT + row)*HID + k];
    } else {
      int d = k >> 7, u = k & 127;
      int sidx = (d==0) ? row : (row < len ? len-1-row : 0);
      si[r][k] = hs[(((size_t)(d*8+b)*128) + u)*128 + sidx];
    }
  }
  __syncthreads();
  int ld = layer*2 + dir;
  int g = tid;
  float bsum = ws[OFF_BSUM + ld*512 + g];
  float acc[8];
  #pragma unroll
  for (int r=0;r<8;r++) acc[r] = bsum;
  const float* wt = ws + OFF_WIHT + ld*256*512;
  for (int k=0;k<HID;k++){
    float w = wt[k*512 + g];
    #pragma unroll
    for (int r=0;r<8;r++) acc[r] += si[r][k]*w;
  }
  float* go = gates + (((size_t)(dir*L_TXT + tt*8)*8) + b)*512 + (g&127)*4 + (g>>7);
  #pragma unroll
  for (int r=0;r<8;r++) go[(size_t)r*8*512] = acc[r];
}

// ---- recurrent scan v10 ----
// one block per (b,dir); 1024 thr; thread (u=tid>>3, c=tid&7) owns ALL 4 gates of
// unit u over h-cols [16c,16c+16). Per step: 8 weight b128 + 2 h b128 reads
// (160 LDS instrs/CU/step, was 256), 32 fdot2, 3-stage butterfly over c lanes
// -> every lane holds complete i,f,g,o (NO gate-exchange shuffles); c,h redundant
// per 8-lane group. h stores to hseq[dir][b][u][s] batched as float4 per 4 steps.
__global__ __launch_bounds__(1024) void k_scan(const float* __restrict__ Gp,
                                               const float* __restrict__ whh_all,
                                               float* __restrict__ hseq, int layer){
  int dir = blockIdx.x & 1; int b = blockIdx.x >> 1;
  int tid = threadIdx.x;
  int l = tid & 63, w = tid >> 6;
  int u = tid >> 3;        // unit 0..127
  int c = tid & 7;         // h-col group

  __shared__ uint wlds[32768];      // 128KB f16 weight pairs, wave-contiguous slots
  __shared__ uint h2buf[2][64];     // rolling h as half2

  // stage weights: rows r*128+u (r = gate i,f,g,o), cols 16c+8p..+7 -> slot j=r*2+p
  #pragma unroll
  for (int r=0;r<4;r++){
    const float* wr = whh_all + ((size_t)((layer*2+dir)*512 + r*128 + u))*HH + 16*c;
    #pragma unroll
    for (int p=0;p<2;p++){
      uint4 vv;
      vv.x = packh2(wr[8*p+0], wr[8*p+1]);
      vv.y = packh2(wr[8*p+2], wr[8*p+3]);
      vv.z = packh2(wr[8*p+4], wr[8*p+5]);
      vv.w = packh2(wr[8*p+6], wr[8*p+7]);
      *(uint4*)(wlds + w*2048 + (r*2+p)*256 + l*4) = vv;   // banks 4l..4l+3
    }
  }
  if (tid < 128) ((uint*)h2buf)[tid] = 0;

  const float* gb = Gp + ((size_t)(dir*L_TXT)*8 + b)*512 + u*4;
  float4 q = *(const float4*)gb;
  float c_reg = 0.f;
  float hm1=0.f, hm2=0.f, hm3=0.f;
  __syncthreads();

  const uint4* wp = (const uint4*)wlds + w*512 + l;   // slot j at wp[j*64]
  float* hout = hseq + (((size_t)(dir*8+b)*128) + u)*128;

  for (int s=0; s<L_TXT; s++){
    const float* gn = gb + (size_t)(s+1 < L_TXT ? s+1 : s)*4096;
    float4 qn = *(const float4*)gn;
    const uint4* hp = (const uint4*)(h2buf[s&1] + c*8);
    uint4 h0 = hp[0], h1 = hp[1];
    float a0, a1, a2, a3;
    { uint4 A=wp[0], Bv=wp[64];
      a0 = fdot2(A.x,h0.x,0.f); a0=fdot2(A.y,h0.y,a0); a0=fdot2(A.z,h0.z,a0); a0=fdot2(A.w,h0.w,a0);
      a0 = fdot2(Bv.x,h1.x,a0); a0=fdot2(Bv.y,h1.y,a0); a0=fdot2(Bv.z,h1.z,a0); a0=fdot2(Bv.w,h1.w,a0); }
    { uint4 A=wp[128], Bv=wp[192];
      a1 = fdot2(A.x,h0.x,0.f); a1=fdot2(A.y,h0.y,a1); a1=fdot2(A.z,h0.z,a1); a1=fdot2(A.w,h0.w,a1);
      a1 = fdot2(Bv.x,h1.x,a1); a1=fdot2(Bv.y,h1.y,a1); a1=fdot2(Bv.z,h1.z,a1); a1=fdot2(Bv.w,h1.w,a1); }
    { uint4 A=wp[256], Bv=wp[320];
      a2 = fdot2(A.x,h0.x,0.f); a2=fdot2(A.y,h0.y,a2); a2=fdot2(A.z,h0.z,a2); a2=fdot2(A.w,h0.w,a2);
      a2 = fdot2(Bv.x,h1.x,a2); a2=fdot2(Bv.y,h1.y,a2); a2=fdot2(Bv.z,h1.z,a2); a2=fdot2(Bv.w,h1.w,a2); }
    { uint4 A=wp[384], Bv=wp[448];
      a3 = fdot2(A.x,h0.x,0.f); a3=fdot2(A.y,h0.y,a3); a3=fdot2(A.z,h0.z,a3); a3=fdot2(A.w,h0.w,a3);
      a3 = fdot2(Bv.x,h1.x,a3); a3=fdot2(Bv.y,h1.y,a3); a3=fdot2(Bv.z,h1.z,a3); a3=fdot2(Bv.w,h1.w,a3); }
    // butterfly-sum over the 8 c-lanes: all lanes end with full dot products
    #pragma unroll
    for (int m=1; m<8; m<<=1){
      a0 += __shfl_xor(a0, m);
      a1 += __shfl_xor(a1, m);
      a2 += __shfl_xor(a2, m);
      a3 += __shfl_xor(a3, m);
    }
    float i_ = fast_sigmoid(a0 + q.x);
    float f_ = fast_sigmoid(a1 + q.y);
    float g_ = fast_tanh   (a2 + q.z);
    float o_ = fast_sigmoid(a3 + q.w);
    c_reg = f_*c_reg + i_*g_;
    float h = o_*fast_tanh(c_reg);
    float hn = __shfl_xor(h, 8);           // neighbor unit u^1's h
    if (c==0 && !(u&1)) h2buf[(s+1)&1][u>>1] = packh2(h, hn);
    if ((s&3)==3 && c==0)
      *(float4*)&hout[s-3] = make_float4(hm3, hm2, hm1, h);
    hm3 = hm2; hm2 = hm1; hm1 = h;
    q = qn;
    __syncthreads();
  }
}

// ---- masked mean pool (direct from hseq1) + p1/tanh + normalize + p2 ----
__global__ __launch_bounds__(256) void k_final(const float* __restrict__ hs,
                                               const int* __restrict__ txt_len,
                                               const float* __restrict__ p1w,
                                               const float* __restrict__ p1b,
                                               const float* __restrict__ p2w,
                                               const float* __restrict__ p2b,
                                               float* __restrict__ d_out){
  int b = blockIdx.x; int tid = threadIdx.x;
  __shared__ float pl[HID];
  __shared__ float ol[EMB];
  __shared__ float nrm;
  int len = txt_len[b];
  // fwd positions<len <-> steps<len identity; bwd positions<len <-> steps<len bijection
  int d = tid >> 7, u = tid & 127;
  const float* hrow = hs + (((size_t)(d*8+b)*128) + u)*128;
  float s = 0.f;
  for (int t=0; t<len; t++) s += hrow[t];
  pl[tid] = s / (float)len;
  __syncthreads();
  if (tid < EMB){
    float a = p1b[tid];
    for (int k=0;k<HID;k++) a += pl[k]*p1w[tid*HID+k];
    ol[tid] = fast_tanh(a);
  }
  __syncthreads();
  if (tid == 0){
    float q = 0.f;
    for (int k=0;k<EMB;k++) q += ol[k]*ol[k];
    nrm = rsqrtf(q);
  }
  __syncthreads();
  if (tid < EMB) d_out[800 + b*EMB + tid] = ol[tid]*nrm;
  if (tid < N_SPK){
    float a = p2b[tid];
    for (int k=0;k<EMB;k++) a += ol[k]*p2w[tid*EMB+k];
    d_out[b*N_SPK + tid] = a;
  }
}

extern "C" void kernel_launch(void* const* d_in, const int* in_sizes, int n_in,
                              void* d_out, int out_size, void* d_ws, size_t ws_size,
                              hipStream_t stream) {
  const float* x       = (const float*)d_in[0];
  const int*   mel_len = (const int*)  d_in[1];
  const float* text    = (const float*)d_in[2];
  const int*   txt_len = (const int*)  d_in[3];
  const float* Wx      = (const float*)d_in[4];
  const float* bx      = (const float*)d_in[5];
  const float* Wq      = (const float*)d_in[6];
  const float* bq      = (const float*)d_in[7];
  const float* Wout    = (const float*)d_in[8];
  const float* bout    = (const float*)d_in[9];
  const float* v       = (const float*)d_in[10];
  const float* wih     = (const float*)d_in[11];
  const float* whh     = (const float*)d_in[12];
  const float* bih     = (const float*)d_in[13];
  const float* bhh     = (const float*)d_in[14];
  const float* p1w     = (const float*)d_in[15];
  const float* p1b     = (const float*)d_in[16];
  const float* p2w     = (const float*)d_in[17];
  const float* p2b     = (const float*)d_in[18];
  float* ws  = (float*)d_ws;
  float* out = (float*)d_out;

  k_prep <<<1618, 256, 0, stream>>>(Wout, bout, v, Wx, Wq, wih, bih, bhh, ws);
  k_xq   <<<1056, 256, 0, stream>>>(x, bx, text, bq, ws);
  k_score<<<1024, 256, 0, stream>>>(mel_len, ws, out);

  float* G = ws + OFF_G;
  k_gates<<<256, 512, 0, stream>>>(ws + OFF_H0, ws + OFF_HS0, txt_len, G, 0, ws);
  k_scan <<<16, 1024, 0, stream>>>(G, whh, ws + OFF_HS0, 0);
  k_gates<<<256, 512, 0, stream>>>(ws + OFF_H0, ws + OFF_HS0, txt_len, G, 1, ws);
  k_scan <<<16, 1024, 0, stream>>>(G, whh, ws + OFF_HS1, 1);

  k_final<<<8, 256, 0, stream>>>(ws + OFF_HS1, txt_len, p1w, p1b, p2w, p2b, out);
}

// Round 12
// 505.357 us; speedup vs baseline: 1.2517x; 1.2517x over previous
//
#include <hip/hip_runtime.h>
#include <hip/hip_bf16.h>
#include <math.h>

#define B 8
#define T_MEL 400
#define N_MEL 80
#define L_TXT 128
#define D_TXT 512
#define E 256
#define HID 256
#define EMB 128
#define N_SPK 100
#define HH 128

// ---- workspace layout (float element offsets) ----
#define OFF_W      0
#define OFF_C      256
#define OFF_WXT    272
#define OFF_WQT    (OFF_WXT + N_MEL*E)        // 20752
#define OFF_WIHT   (OFF_WQT + D_TXT*E)        // 151824
#define OFF_BSUM   (OFF_WIHT + 2*2*256*512)   // 676112
#define OFF_X1     (OFF_BSUM + 2048)          // 678160
#define OFF_Q1     (OFF_X1 + B*T_MEL*E)       // 1497360
#define OFF_G      OFF_X1                      // gates overlay x1+q1 (dead by then)
#define OFF_H0     (OFF_Q1 + B*L_TXT*E)       // 1759504
#define OFF_O1     (OFF_H0 + B*L_TXT*E)       // 2021648
#define OFF_HS0    OFF_H0                      // hseq layer0 overlays H0 (dead after k_gates0)
#define OFF_HS1    OFF_O1                      // hseq layer1 in O1 region

typedef _Float16 half2v __attribute__((ext_vector_type(2)));

__device__ __forceinline__ float fast_sigmoid(float x){ return 1.f/(1.f+__expf(-x)); }
__device__ __forceinline__ float fast_tanh(float x){ float e=__expf(2.f*x); return 1.f - 2.f/(e+1.f); }

__device__ __forceinline__ float fdot2(uint a, uint b, float c){
  half2v ha = __builtin_bit_cast(half2v, a);
  half2v hb = __builtin_bit_cast(half2v, b);
#if __has_builtin(__builtin_amdgcn_fdot2)
  return __builtin_amdgcn_fdot2(ha, hb, c, false);
#else
  float r;
  asm("v_dot2_f32_f16 %0, %1, %2, %3" : "=v"(r) : "v"(a), "v"(b), "v"(c));
  return r;
#endif
}
__device__ __forceinline__ uint packh2(float a, float b){
  union { _Float16 h[2]; uint u; } x;
  x.h[0] = (_Float16)a; x.h[1] = (_Float16)b; return x.u;
}

// ---- prep: w = Wout^T v, c = bout.v ; transposes WxT, WqT, WihT ; bias sums ----
// MUST be its own kernel: k_xq's blocks consume WXT/WQT (no intra-kernel ordering).
__global__ __launch_bounds__(256) void k_prep(const float* __restrict__ Wout, const float* __restrict__ bout,
                       const float* __restrict__ v,    const float* __restrict__ Wx,
                       const float* __restrict__ Wq,   const float* __restrict__ wih,
                       const float* __restrict__ bih,  const float* __restrict__ bhh,
                       float* __restrict__ ws){
  int blk = blockIdx.x, tid = threadIdx.x;
  if (blk == 0){
    float acc = 0.f;
    for (int j=0;j<E;j++) acc += Wout[j*E + tid] * v[j];
    ws[OFF_W + tid] = acc;
    if (tid==0){ float c=0.f; for(int j=0;j<E;j++) c += bout[j]*v[j]; ws[OFF_C]=c; }
  } else if (blk <= N_MEL){
    int m = blk-1;
    ws[OFF_WXT + m*E + tid] = Wx[tid*N_MEL + m];
  } else if (blk <= N_MEL + D_TXT){
    int k = blk-1-N_MEL;
    ws[OFF_WQT + k*E + tid] = Wq[tid*D_TXT + k];
  } else if (blk <= N_MEL + D_TXT + 1024){
    int idx = blk-1-N_MEL-D_TXT;      // ld*256 + k
    int ld = idx >> 8, k = idx & 255;
    for (int g = tid; g < 512; g += 256)
      ws[OFF_WIHT + idx*512 + g] = wih[(ld*512+g)*256 + k];
  } else {
    for (int i = tid; i < 2048; i += 256)
      ws[OFF_BSUM + i] = bih[i] + bhh[i];
  }
}

// ---- x1 (blk<800) | q1 (blk 800..1055) ; reads WXT/WQT written by k_prep ----
__global__ __launch_bounds__(256) void k_xq(const float* __restrict__ x,    const float* __restrict__ bx,
                                            const float* __restrict__ text, const float* __restrict__ bq,
                                            float* __restrict__ ws){
  __shared__ float sbuf[2048];
  int blk = blockIdx.x, tid = threadIdx.x;
  if (blk < 800){
    int b = blk/100; int t0 = (blk%100)*4;
    float (*sx)[4] = (float(*)[4])sbuf;
    for (int i = tid; i < N_MEL*4; i += 256){
      int m = i>>2, ii = i&3;
      sx[m][ii] = x[(b*N_MEL+m)*T_MEL + t0 + ii];
    }
    __syncthreads();
    float bxe = bx[tid];
    float a0=bxe,a1=bxe,a2=bxe,a3=bxe;
    const float* wxt = ws + OFF_WXT;
    #pragma unroll 4
    for (int m=0;m<N_MEL;m++){
      float w = wxt[m*E + tid];
      a0 += sx[m][0]*w; a1 += sx[m][1]*w; a2 += sx[m][2]*w; a3 += sx[m][3]*w;
    }
    float* x1 = ws + OFF_X1 + (b*T_MEL + t0)*E + tid;
    x1[0]=a0; x1[E]=a1; x1[2*E]=a2; x1[3*E]=a3;
  } else {
    int bb = blk - 800;
    int b = bb/32; int l0 = (bb%32)*4;
    float (*st)[D_TXT] = (float(*)[D_TXT])sbuf;
    for (int i = tid; i < 4*D_TXT; i += 256){
      int li = i / D_TXT, k = i % D_TXT;
      st[li][k] = text[(b*L_TXT + l0 + li)*D_TXT + k];
    }
    __syncthreads();
    float bqe = bq[tid];
    float a0=bqe,a1=bqe,a2=bqe,a3=bqe;
    const float* wqt = ws + OFF_WQT;
    #pragma unroll 2
    for (int k=0;k<D_TXT;k++){
      float w = wqt[k*E + tid];
      a0 += st[0][k]*w; a1 += st[1][k]*w; a2 += st[2][k]*w; a3 += st[3][k]*w;
    }
    float* q1 = ws + OFF_Q1 + (b*L_TXT + l0)*E + tid;
    q1[0]=a0; q1[E]=a1; q1[2*E]=a2; q1[3*E]=a3;
  }
}

// ---- scores + masked softmax + context + h0 ; one block per (b,l) ----
__global__ __launch_bounds__(256) void k_score(const int* __restrict__ mel_len,
                                               float* __restrict__ ws,
                                               float* __restrict__ d_out){
  int blk = blockIdx.x; int b = blk >> 7; int l = blk & 127;
  int tid = threadIdx.x; int lane = tid & 63; int wv = tid >> 6;
  __shared__ float sl[T_MEL];
  __shared__ float red[8];
  const float* x1 = ws + OFF_X1 + b*T_MEL*E;
  const float* q1 = ws + OFF_Q1 + (b*L_TXT+l)*E;
  float qv[4], wv4[4];
  #pragma unroll
  for (int j=0;j<4;j++){ qv[j] = q1[lane+64*j]; wv4[j] = ws[OFF_W + lane + 64*j]; }
  float cc = ws[OFF_C];
  int len = mel_len[b];
  for (int t = wv; t < T_MEL; t += 4){
    const float* xr = x1 + t*E;
    float s = 0.f;
    #pragma unroll
    for (int j=0;j<4;j++) s += wv4[j]*fast_tanh(xr[lane+64*j] + qv[j]);
    #pragma unroll
    for (int off=32; off>=1; off>>=1) s += __shfl_xor(s, off);
    if (lane==0) sl[t] = s + cc;
  }
  __syncthreads();
  float mx = -3.0e38f;
  for (int t = tid; t < T_MEL; t += 256) if (t < len) mx = fmaxf(mx, sl[t]);
  #pragma unroll
  for (int off=32; off>=1; off>>=1) mx = fmaxf(mx, __shfl_xor(mx, off));
  if (lane==0) red[wv] = mx;
  __syncthreads();
  mx = fmaxf(fmaxf(red[0],red[1]),fmaxf(red[2],red[3]));
  float se = 0.f;
  for (int t = tid; t < T_MEL; t += 256){
    float p = (t < len) ? __expf(sl[t]-mx) : 0.f;
    sl[t] = p; se += p;
  }
  #pragma unroll
  for (int off=32; off>=1; off>>=1) se += __shfl_xor(se, off);
  if (lane==0) red[4+wv] = se;
  __syncthreads();
  float rsum = 1.f/(red[4]+red[5]+red[6]+red[7]);
  float* sc_out = d_out + 1824 + (b*L_TXT + l)*T_MEL;
  for (int t = tid; t < T_MEL; t += 256){
    float p = sl[t]*rsum;
    sl[t] = p; sc_out[t] = p;
  }
  __syncthreads();
  float a = 0.f;
  int e = tid;
  #pragma unroll 4
  for (int t = 0; t < len; t++) a += sl[t]*x1[t*E + e];
  ws[OFF_H0 + (b*L_TXT+l)*E + e] = q1[e] + a;
}

// ---- gates: in @ WihT + (bih+bhh) ; layer0 reads H0[b][l][256];
//      layer1 reads hseq0[d][b][u][s] with pack-reverse fold composed in.
//      output: G[dir][t][b][row]  (row = gate*128+unit, PyTorch order i,f,g,o) ----
__global__ __launch_bounds__(512) void k_gates(const float* __restrict__ in,
                                               const float* __restrict__ hs,
                                               const int* __restrict__ txt_len,
                                               float* __restrict__ gates, int layer,
                                               float* __restrict__ ws){
  int idx = blockIdx.x; int tt = idx & 15; int dir = (idx>>4)&1; int b = idx>>5;
  int tid = threadIdx.x;
  __shared__ float si[8][HID];
  int len = txt_len[b];
  for (int i = tid; i < 8*HID; i += 512){
    int r = i >> 8, k = i & 255;
    int t = tt*8 + r;
    int row = dir ? max(0, len-1-t) : t;
    if (layer == 0){
      si[r][k] = in[(b*L_TXT + row)*HID + k];
    } else {
      int d = k >> 7, u = k & 127;
      int sidx = (d==0) ? row : (row < len ? len-1-row : 0);
      si[r][k] = hs[(((size_t)(d*8+b)*128) + u)*128 + sidx];
    }
  }
  __syncthreads();
  int ld = layer*2 + dir;
  int g = tid;
  float bsum = ws[OFF_BSUM + ld*512 + g];
  float acc[8];
  #pragma unroll
  for (int r=0;r<8;r++) acc[r] = bsum;
  const float* wt = ws + OFF_WIHT + ld*256*512;
  for (int k=0;k<HID;k++){
    float w = wt[k*512 + g];
    #pragma unroll
    for (int r=0;r<8;r++) acc[r] += si[r][k]*w;
  }
  float* go = gates + (((size_t)(dir*L_TXT + tt*8)*8) + b)*512 + g;
  #pragma unroll
  for (int r=0;r<8;r++) go[(size_t)r*8*512] = acc[r];
}

// ---- recurrent scan v11 ----
// one block per (b,dir); 512 thr = 8 waves. Thread (w,l): gt=l>>4, u=w*16+(l&15),
// owns FULL gate-row gt*128+u. Per step per thread: 16 b128 weight reads (the
// 128KB/step floor), 4 broadcast b128 h reads, 64 fdot2, own activation (1 exp),
// then 3-shfl butterfly (bits 4,5) delivers activated i,f,g,o to every lane;
// c,h computed 4x-redundant. 4th shfl pairs h for the half2 write. 1 barrier/step.
// DS-pipe ops ~24/thread x 8 waves ~ 194 wave-instrs/step (v9 was ~336 on 16 waves).
__global__ __launch_bounds__(512) void k_scan(const float* __restrict__ Gp,
                                              const float* __restrict__ whh_all,
                                              float* __restrict__ hseq, int layer){
  int dir = blockIdx.x & 1; int b = blockIdx.x >> 1;
  int tid = threadIdx.x;
  int l = tid & 63, w = tid >> 6;
  int gt = l >> 4;           // 0:i 1:f 2:g 3:o
  int li = l & 15;
  int u  = w*16 + li;        // unit 0..127
  int row = gt*128 + u;      // gate row

  __shared__ uint wlds[32768];      // 128KB f16 pairs: [w][phase j][lane][4]
  __shared__ uint h2buf[2][64];     // rolling h as half2

  // stage own row: cols j*8..j*8+7 -> wlds + w*4096 + j*256 + l*4 (conflict-free)
  const float* wr = whh_all + ((size_t)((layer*2+dir)*512 + row))*HH;
  #pragma unroll
  for (int j=0;j<16;j++){
    uint4 vv;
    vv.x = packh2(wr[j*8+0], wr[j*8+1]);
    vv.y = packh2(wr[j*8+2], wr[j*8+3]);
    vv.z = packh2(wr[j*8+4], wr[j*8+5]);
    vv.w = packh2(wr[j*8+6], wr[j*8+7]);
    *(uint4*)(wlds + w*4096 + j*256 + l*4) = vv;
  }
  if (tid < 128) ((uint*)h2buf)[tid] = 0;

  const float* gb = Gp + ((size_t)(dir*L_TXT)*8 + b)*512 + row;
  float gi = gb[0];
  float c_reg = 0.f;
  float hm1=0.f, hm2=0.f, hm3=0.f;
  bool isg = (gt==2);
  __syncthreads();

  const uint4* wp = (const uint4*)(wlds + w*4096 + l*4);   // phase j at wp[j*64]
  float* hout = hseq + (((size_t)(dir*8+b)*128) + u)*128;

  for (int s=0; s<L_TXT; s++){
    float gnext = gb[(size_t)(s+1 < L_TXT ? s+1 : s)*4096];
    float acc = gi;
    const uint4* hp = (const uint4*)(h2buf[s&1]);          // broadcast reads
    #pragma unroll
    for (int j=0;j<16;j+=2){
      uint4 A0 = wp[j*64],     H0 = hp[j];
      uint4 A1 = wp[(j+1)*64], H1 = hp[j+1];
      acc = fdot2(A0.x,H0.x,acc); acc = fdot2(A0.y,H0.y,acc);
      acc = fdot2(A0.z,H0.z,acc); acc = fdot2(A0.w,H0.w,acc);
      acc = fdot2(A1.x,H1.x,acc); acc = fdot2(A1.y,H1.y,acc);
      acc = fdot2(A1.z,H1.z,acc); acc = fdot2(A1.w,H1.w,acc);
    }
    // activate own gate (1 exp): tanh(a)=2*sig(2a)-1 for g
    float xa = isg ? 2.f*acc : acc;
    float sg = 1.f/(1.f+__expf(-xa));
    float val = isg ? 2.f*sg - 1.f : sg;
    // butterfly over gate bits (lane bits 4,5): every lane gets i,f,g,o (activated)
    float x  = __shfl_xor(val, 16);
    float y0 = __shfl_xor(val, 32);
    float y1 = __shfl_xor(x,   32);
    float iv = (gt==0)?val : (gt==1)?x  : (gt==2)?y0 : y1;
    float fv = (gt==0)?x   : (gt==1)?val: (gt==2)?y1 : y0;
    float gv = (gt==0)?y0  : (gt==1)?y1 : (gt==2)?val: x;
    float ov = (gt==0)?y1  : (gt==1)?y0 : (gt==2)?x  : val;
    c_reg = fv*c_reg + iv*gv;
    float h = ov*fast_tanh(c_reg);
    float hn = __shfl_xor(h, 1);          // neighbor unit u^1's h
    if (gt==0 && !(li&1)) h2buf[(s+1)&1][u>>1] = packh2(h, hn);
    if (gt==0 && (s&3)==3)
      *(float4*)&hout[s-3] = make_float4(hm3, hm2, hm1, h);
    hm3 = hm2; hm2 = hm1; hm1 = h;
    gi = gnext;
    __syncthreads();
  }
}

// ---- masked mean pool (direct from hseq1) + p1/tanh + normalize + p2 ----
__global__ __launch_bounds__(256) void k_final(const float* __restrict__ hs,
                                               const int* __restrict__ txt_len,
                                               const float* __restrict__ p1w,
                                               const float* __restrict__ p1b,
                                               const float* __restrict__ p2w,
                                               const float* __restrict__ p2b,
                                               float* __restrict__ d_out){
  int b = blockIdx.x; int tid = threadIdx.x;
  __shared__ float pl[HID];
  __shared__ float ol[EMB];
  __shared__ float nrm;
  int len = txt_len[b];
  // fwd positions<len <-> steps<len identity; bwd positions<len <-> steps<len bijection
  int d = tid >> 7, u = tid & 127;
  const float* hrow = hs + (((size_t)(d*8+b)*128) + u)*128;
  float s = 0.f;
  for (int t=0; t<len; t++) s += hrow[t];
  pl[tid] = s / (float)len;
  __syncthreads();
  if (tid < EMB){
    float a = p1b[tid];
    for (int k=0;k<HID;k++) a += pl[k]*p1w[tid*HID+k];
    ol[tid] = fast_tanh(a);
  }
  __syncthreads();
  if (tid == 0){
    float q = 0.f;
    for (int k=0;k<EMB;k++) q += ol[k]*ol[k];
    nrm = rsqrtf(q);
  }
  __syncthreads();
  if (tid < EMB) d_out[800 + b*EMB + tid] = ol[tid]*nrm;
  if (tid < N_SPK){
    float a = p2b[tid];
    for (int k=0;k<EMB;k++) a += ol[k]*p2w[tid*EMB+k];
    d_out[b*N_SPK + tid] = a;
  }
}

extern "C" void kernel_launch(void* const* d_in, const int* in_sizes, int n_in,
                              void* d_out, int out_size, void* d_ws, size_t ws_size,
                              hipStream_t stream) {
  const float* x       = (const float*)d_in[0];
  const int*   mel_len = (const int*)  d_in[1];
  const float* text    = (const float*)d_in[2];
  const int*   txt_len = (const int*)  d_in[3];
  const float* Wx      = (const float*)d_in[4];
  const float* bx      = (const float*)d_in[5];
  const float* Wq      = (const float*)d_in[6];
  const float* bq      = (const float*)d_in[7];
  const float* Wout    = (const float*)d_in[8];
  const float* bout    = (const float*)d_in[9];
  const float* v       = (const float*)d_in[10];
  const float* wih     = (const float*)d_in[11];
  const float* whh     = (const float*)d_in[12];
  const float* bih     = (const float*)d_in[13];
  const float* bhh     = (const float*)d_in[14];
  const float* p1w     = (const float*)d_in[15];
  const float* p1b     = (const float*)d_in[16];
  const float* p2w     = (const float*)d_in[17];
  const float* p2b     = (const float*)d_in[18];
  float* ws  = (float*)d_ws;
  float* out = (float*)d_out;

  k_prep <<<1618, 256, 0, stream>>>(Wout, bout, v, Wx, Wq, wih, bih, bhh, ws);
  k_xq   <<<1056, 256, 0, stream>>>(x, bx, text, bq, ws);
  k_score<<<1024, 256, 0, stream>>>(mel_len, ws, out);

  float* G = ws + OFF_G;
  k_gates<<<256, 512, 0, stream>>>(ws + OFF_H0, ws + OFF_HS0, txt_len, G, 0, ws);
  k_scan <<<16, 512, 0, stream>>>(G, whh, ws + OFF_HS0, 0);
  k_gates<<<256, 512, 0, stream>>>(ws + OFF_H0, ws + OFF_HS0, txt_len, G, 1, ws);
  k_scan <<<16, 512, 0, stream>>>(G, whh, ws + OFF_HS1, 1);

  k_final<<<8, 256, 0, stream>>>(ws + OFF_HS1, txt_len, p1w, p1b, p2w, p2b, out);
}

// Round 13
// 489.007 us; speedup vs baseline: 1.2936x; 1.0334x over previous
//
#include <hip/hip_runtime.h>
#include <hip/hip_bf16.h>
#include <math.h>

#define B 8
#define T_MEL 400
#define N_MEL 80
#define L_TXT 128
#define D_TXT 512
#define E 256
#define HID 256
#define EMB 128
#define N_SPK 100
#define HH 128

// ---- workspace layout (float element offsets) ----
#define OFF_W      0
#define OFF_C      256
#define OFF_WXT    272
#define OFF_WQT    (OFF_WXT + N_MEL*E)        // 20752
#define OFF_WIHT   (OFF_WQT + D_TXT*E)        // 151824
#define OFF_BSUM   (OFF_WIHT + 2*2*256*512)   // 676112
#define OFF_X1     (OFF_BSUM + 2048)          // 678160
#define OFF_Q1     (OFF_X1 + B*T_MEL*E)       // 1497360
#define OFF_G      OFF_X1                      // gates overlay x1+q1 (dead by then)
#define OFF_H0     (OFF_Q1 + B*L_TXT*E)       // 1759504
#define OFF_O1     (OFF_H0 + B*L_TXT*E)       // 2021648
#define OFF_HS0    OFF_H0                      // hseq layer0 overlays H0 (dead after k_gates0)
#define OFF_HS1    OFF_O1                      // hseq layer1 in O1 region

typedef _Float16 half2v __attribute__((ext_vector_type(2)));

__device__ __forceinline__ float fast_sigmoid(float x){ return 1.f/(1.f+__expf(-x)); }
__device__ __forceinline__ float fast_tanh(float x){ float e=__expf(2.f*x); return 1.f - 2.f/(e+1.f); }

__device__ __forceinline__ float fdot2(uint a, uint b, float c){
  half2v ha = __builtin_bit_cast(half2v, a);
  half2v hb = __builtin_bit_cast(half2v, b);
#if __has_builtin(__builtin_amdgcn_fdot2)
  return __builtin_amdgcn_fdot2(ha, hb, c, false);
#else
  float r;
  asm("v_dot2_f32_f16 %0, %1, %2, %3" : "=v"(r) : "v"(a), "v"(b), "v"(c));
  return r;
#endif
}
__device__ __forceinline__ uint packh2(float a, float b){
  union { _Float16 h[2]; uint u; } x;
  x.h[0] = (_Float16)a; x.h[1] = (_Float16)b; return x.u;
}

// ---- prep: w = Wout^T v, c = bout.v ; transposes WxT, WqT, WihT ; bias sums ----
// MUST be its own kernel: k_xq's blocks consume WXT/WQT (no intra-kernel ordering).
__global__ __launch_bounds__(256) void k_prep(const float* __restrict__ Wout, const float* __restrict__ bout,
                       const float* __restrict__ v,    const float* __restrict__ Wx,
                       const float* __restrict__ Wq,   const float* __restrict__ wih,
                       const float* __restrict__ bih,  const float* __restrict__ bhh,
                       float* __restrict__ ws){
  int blk = blockIdx.x, tid = threadIdx.x;
  if (blk == 0){
    float acc = 0.f;
    for (int j=0;j<E;j++) acc += Wout[j*E + tid] * v[j];
    ws[OFF_W + tid] = acc;
    if (tid==0){ float c=0.f; for(int j=0;j<E;j++) c += bout[j]*v[j]; ws[OFF_C]=c; }
  } else if (blk <= N_MEL){
    int m = blk-1;
    ws[OFF_WXT + m*E + tid] = Wx[tid*N_MEL + m];
  } else if (blk <= N_MEL + D_TXT){
    int k = blk-1-N_MEL;
    ws[OFF_WQT + k*E + tid] = Wq[tid*D_TXT + k];
  } else if (blk <= N_MEL + D_TXT + 1024){
    int idx = blk-1-N_MEL-D_TXT;      // ld*256 + k
    int ld = idx >> 8, k = idx & 255;
    for (int g = tid; g < 512; g += 256)
      ws[OFF_WIHT + idx*512 + g] = wih[(ld*512+g)*256 + k];
  } else {
    for (int i = tid; i < 2048; i += 256)
      ws[OFF_BSUM + i] = bih[i] + bhh[i];
  }
}

// ---- x1 (blk<800) | q1 (blk 800..1055) ; reads WXT/WQT written by k_prep ----
__global__ __launch_bounds__(256) void k_xq(const float* __restrict__ x,    const float* __restrict__ bx,
                                            const float* __restrict__ text, const float* __restrict__ bq,
                                            float* __restrict__ ws){
  __shared__ float sbuf[2048];
  int blk = blockIdx.x, tid = threadIdx.x;
  if (blk < 800){
    int b = blk/100; int t0 = (blk%100)*4;
    float (*sx)[4] = (float(*)[4])sbuf;
    for (int i = tid; i < N_MEL*4; i += 256){
      int m = i>>2, ii = i&3;
      sx[m][ii] = x[(b*N_MEL+m)*T_MEL + t0 + ii];
    }
    __syncthreads();
    float bxe = bx[tid];
    float a0=bxe,a1=bxe,a2=bxe,a3=bxe;
    const float* wxt = ws + OFF_WXT;
    #pragma unroll 4
    for (int m=0;m<N_MEL;m++){
      float w = wxt[m*E + tid];
      a0 += sx[m][0]*w; a1 += sx[m][1]*w; a2 += sx[m][2]*w; a3 += sx[m][3]*w;
    }
    float* x1 = ws + OFF_X1 + (b*T_MEL + t0)*E + tid;
    x1[0]=a0; x1[E]=a1; x1[2*E]=a2; x1[3*E]=a3;
  } else {
    int bb = blk - 800;
    int b = bb/32; int l0 = (bb%32)*4;
    float (*st)[D_TXT] = (float(*)[D_TXT])sbuf;
    for (int i = tid; i < 4*D_TXT; i += 256){
      int li = i / D_TXT, k = i % D_TXT;
      st[li][k] = text[(b*L_TXT + l0 + li)*D_TXT + k];
    }
    __syncthreads();
    float bqe = bq[tid];
    float a0=bqe,a1=bqe,a2=bqe,a3=bqe;
    const float* wqt = ws + OFF_WQT;
    #pragma unroll 2
    for (int k=0;k<D_TXT;k++){
      float w = wqt[k*E + tid];
      a0 += st[0][k]*w; a1 += st[1][k]*w; a2 += st[2][k]*w; a3 += st[3][k]*w;
    }
    float* q1 = ws + OFF_Q1 + (b*L_TXT + l0)*E + tid;
    q1[0]=a0; q1[E]=a1; q1[2*E]=a2; q1[3*E]=a3;
  }
}

// ---- scores + masked softmax + context + h0 ; one block per (b,l) ----
// v2: phase1 uses 16-lane groups (4 t's per wave-iter, 1 shuffle/t not 6);
//     context loop un-guarded (sl=0 past len) + 4x float4-batched.
__global__ __launch_bounds__(256) void k_score(const int* __restrict__ mel_len,
                                               float* __restrict__ ws,
                                               float* __restrict__ d_out){
  int blk = blockIdx.x; int b = blk >> 7; int l = blk & 127;
  int tid = threadIdx.x; int lane = tid & 63; int wv = tid >> 6;
  __shared__ __align__(16) float sl[T_MEL];
  __shared__ float red[8];
  const float* x1 = ws + OFF_X1 + b*T_MEL*E;
  const float* q1 = ws + OFF_Q1 + (b*L_TXT+l)*E;
  int g = lane >> 4, i = lane & 15;      // group (which t), e-chunk
  float qv[16], wvv[16];
  {
    const float4* q4 = (const float4*)(q1 + i*16);
    const float4* w4 = (const float4*)(ws + OFF_W + i*16);
    #pragma unroll
    for (int j=0;j<4;j++){
      float4 a = q4[j]; qv[4*j]=a.x; qv[4*j+1]=a.y; qv[4*j+2]=a.z; qv[4*j+3]=a.w;
      float4 c = w4[j]; wvv[4*j]=c.x; wvv[4*j+1]=c.y; wvv[4*j+2]=c.z; wvv[4*j+3]=c.w;
    }
  }
  float cc = ws[OFF_C];
  int len = mel_len[b];
  #pragma unroll 2
  for (int iter=0; iter<25; iter++){
    int t = iter*16 + wv*4 + g;
    const float4* xr = (const float4*)(x1 + t*E + i*16);
    float s = 0.f;
    #pragma unroll
    for (int j=0;j<4;j++){
      float4 xv = xr[j];
      s += wvv[4*j+0]*fast_tanh(xv.x + qv[4*j+0]);
      s += wvv[4*j+1]*fast_tanh(xv.y + qv[4*j+1]);
      s += wvv[4*j+2]*fast_tanh(xv.z + qv[4*j+2]);
      s += wvv[4*j+3]*fast_tanh(xv.w + qv[4*j+3]);
    }
    s += __shfl_xor(s,1); s += __shfl_xor(s,2);
    s += __shfl_xor(s,4); s += __shfl_xor(s,8);
    if (i==0) sl[t] = s + cc;
  }
  __syncthreads();
  float mx = -3.0e38f;
  for (int t = tid; t < T_MEL; t += 256) if (t < len) mx = fmaxf(mx, sl[t]);
  #pragma unroll
  for (int off=32; off>=1; off>>=1) mx = fmaxf(mx, __shfl_xor(mx, off));
  if (lane==0) red[wv] = mx;
  __syncthreads();
  mx = fmaxf(fmaxf(red[0],red[1]),fmaxf(red[2],red[3]));
  float se = 0.f;
  for (int t = tid; t < T_MEL; t += 256){
    float p = (t < len) ? __expf(sl[t]-mx) : 0.f;
    sl[t] = p; se += p;
  }
  #pragma unroll
  for (int off=32; off>=1; off>>=1) se += __shfl_xor(se, off);
  if (lane==0) red[4+wv] = se;
  __syncthreads();
  float rsum = 1.f/(red[4]+red[5]+red[6]+red[7]);
  float* sc_out = d_out + 1824 + (b*L_TXT + l)*T_MEL;
  for (int t = tid; t < T_MEL; t += 256){
    float p = sl[t]*rsum;
    sl[t] = p; sc_out[t] = p;
  }
  __syncthreads();
  float a = 0.f;
  int e = tid;
  for (int t = 0; t < T_MEL; t += 4){
    float4 p4 = *(const float4*)&sl[t];     // sl=0 past len -> no guard needed
    a += p4.x*x1[(t  )*E+e] + p4.y*x1[(t+1)*E+e]
       + p4.z*x1[(t+2)*E+e] + p4.w*x1[(t+3)*E+e];
  }
  ws[OFF_H0 + (b*L_TXT+l)*E + e] = q1[e] + a;
}

// ---- gates: in @ WihT + (bih+bhh) ; layer0 reads H0[b][l][256];
//      layer1 reads hseq0[d][b][u][s] with pack-reverse fold composed in.
//      output: G[dir][t][b][row]  (row = gate*128+unit, PyTorch order i,f,g,o) ----
__global__ __launch_bounds__(512) void k_gates(const float* __restrict__ in,
                                               const float* __restrict__ hs,
                                               const int* __restrict__ txt_len,
                                               float* __restrict__ gates, int layer,
                                               float* __restrict__ ws){
  int idx = blockIdx.x; int tt = idx & 15; int dir = (idx>>4)&1; int b = idx>>5;
  int tid = threadIdx.x;
  __shared__ float si[8][HID];
  int len = txt_len[b];
  for (int i = tid; i < 8*HID; i += 512){
    int r = i >> 8, k = i & 255;
    int t = tt*8 + r;
    int row = dir ? max(0, len-1-t) : t;
    if (layer == 0){
      si[r][k] = in[(b*L_TXT + row)*HID + k];
    } else {
      int d = k >> 7, u = k & 127;
      int sidx = (d==0) ? row : (row < len ? len-1-row : 0);
      si[r][k] = hs[(((size_t)(d*8+b)*128) + u)*128 + sidx];
    }
  }
  __syncthreads();
  int ld = layer*2 + dir;
  int g = tid;
  float bsum = ws[OFF_BSUM + ld*512 + g];
  float acc[8];
  #pragma unroll
  for (int r=0;r<8;r++) acc[r] = bsum;
  const float* wt = ws + OFF_WIHT + ld*256*512;
  for (int k=0;k<HID;k++){
    float w = wt[k*512 + g];
    #pragma unroll
    for (int r=0;r<8;r++) acc[r] += si[r][k]*w;
  }
  float* go = gates + (((size_t)(dir*L_TXT + tt*8)*8) + b)*512 + g;
  #pragma unroll
  for (int r=0;r<8;r++) go[(size_t)r*8*512] = acc[r];
}

// ---- recurrent scan v11 (unchanged from R12: 126us, conflicts 0) ----
__global__ __launch_bounds__(512) void k_scan(const float* __restrict__ Gp,
                                              const float* __restrict__ whh_all,
                                              float* __restrict__ hseq, int layer){
  int dir = blockIdx.x & 1; int b = blockIdx.x >> 1;
  int tid = threadIdx.x;
  int l = tid & 63, w = tid >> 6;
  int gt = l >> 4;           // 0:i 1:f 2:g 3:o
  int li = l & 15;
  int u  = w*16 + li;        // unit 0..127
  int row = gt*128 + u;      // gate row

  __shared__ uint wlds[32768];      // 128KB f16 pairs: [w][phase j][lane][4]
  __shared__ uint h2buf[2][64];     // rolling h as half2

  const float* wr = whh_all + ((size_t)((layer*2+dir)*512 + row))*HH;
  #pragma unroll
  for (int j=0;j<16;j++){
    uint4 vv;
    vv.x = packh2(wr[j*8+0], wr[j*8+1]);
    vv.y = packh2(wr[j*8+2], wr[j*8+3]);
    vv.z = packh2(wr[j*8+4], wr[j*8+5]);
    vv.w = packh2(wr[j*8+6], wr[j*8+7]);
    *(uint4*)(wlds + w*4096 + j*256 + l*4) = vv;
  }
  if (tid < 128) ((uint*)h2buf)[tid] = 0;

  const float* gb = Gp + ((size_t)(dir*L_TXT)*8 + b)*512 + row;
  float gi = gb[0];
  float c_reg = 0.f;
  float hm1=0.f, hm2=0.f, hm3=0.f;
  bool isg = (gt==2);
  __syncthreads();

  const uint4* wp = (const uint4*)(wlds + w*4096 + l*4);   // phase j at wp[j*64]
  float* hout = hseq + (((size_t)(dir*8+b)*128) + u)*128;

  for (int s=0; s<L_TXT; s++){
    float gnext = gb[(size_t)(s+1 < L_TXT ? s+1 : s)*4096];
    float acc = gi;
    const uint4* hp = (const uint4*)(h2buf[s&1]);          // broadcast reads
    #pragma unroll
    for (int j=0;j<16;j+=2){
      uint4 A0 = wp[j*64],     H0 = hp[j];
      uint4 A1 = wp[(j+1)*64], H1 = hp[j+1];
      acc = fdot2(A0.x,H0.x,acc); acc = fdot2(A0.y,H0.y,acc);
      acc = fdot2(A0.z,H0.z,acc); acc = fdot2(A0.w,H0.w,acc);
      acc = fdot2(A1.x,H1.x,acc); acc = fdot2(A1.y,H1.y,acc);
      acc = fdot2(A1.z,H1.z,acc); acc = fdot2(A1.w,H1.w,acc);
    }
    float xa = isg ? 2.f*acc : acc;
    float sg = 1.f/(1.f+__expf(-xa));
    float val = isg ? 2.f*sg - 1.f : sg;
    float x  = __shfl_xor(val, 16);
    float y0 = __shfl_xor(val, 32);
    float y1 = __shfl_xor(x,   32);
    float iv = (gt==0)?val : (gt==1)?x  : (gt==2)?y0 : y1;
    float fv = (gt==0)?x   : (gt==1)?val: (gt==2)?y1 : y0;
    float gv = (gt==0)?y0  : (gt==1)?y1 : (gt==2)?val: x;
    float ov = (gt==0)?y1  : (gt==1)?y0 : (gt==2)?x  : val;
    c_reg = fv*c_reg + iv*gv;
    float h = ov*fast_tanh(c_reg);
    float hn = __shfl_xor(h, 1);
    if (gt==0 && !(li&1)) h2buf[(s+1)&1][u>>1] = packh2(h, hn);
    if (gt==0 && (s&3)==3)
      *(float4*)&hout[s-3] = make_float4(hm3, hm2, hm1, h);
    hm3 = hm2; hm2 = hm1; hm1 = h;
    gi = gnext;
    __syncthreads();
  }
}

// ---- masked mean pool (direct from hseq1) + p1/tanh + normalize + p2 ----
__global__ __launch_bounds__(256) void k_final(const float* __restrict__ hs,
                                               const int* __restrict__ txt_len,
                                               const float* __restrict__ p1w,
                                               const float* __restrict__ p1b,
                                               const float* __restrict__ p2w,
                                               const float* __restrict__ p2b,
                                               float* __restrict__ d_out){
  int b = blockIdx.x; int tid = threadIdx.x;
  __shared__ float pl[HID];
  __shared__ float ol[EMB];
  __shared__ float nrm;
  int len = txt_len[b];
  int d = tid >> 7, u = tid & 127;
  const float* hrow = hs + (((size_t)(d*8+b)*128) + u)*128;
  float s = 0.f;
  for (int t=0; t<len; t++) s += hrow[t];
  pl[tid] = s / (float)len;
  __syncthreads();
  if (tid < EMB){
    float a = p1b[tid];
    for (int k=0;k<HID;k++) a += pl[k]*p1w[tid*HID+k];
    ol[tid] = fast_tanh(a);
  }
  __syncthreads();
  if (tid == 0){
    float q = 0.f;
    for (int k=0;k<EMB;k++) q += ol[k]*ol[k];
    nrm = rsqrtf(q);
  }
  __syncthreads();
  if (tid < EMB) d_out[800 + b*EMB + tid] = ol[tid]*nrm;
  if (tid < N_SPK){
    float a = p2b[tid];
    for (int k=0;k<EMB;k++) a += ol[k]*p2w[tid*EMB+k];
    d_out[b*N_SPK + tid] = a;
  }
}

extern "C" void kernel_launch(void* const* d_in, const int* in_sizes, int n_in,
                              void* d_out, int out_size, void* d_ws, size_t ws_size,
                              hipStream_t stream) {
  const float* x       = (const float*)d_in[0];
  const int*   mel_len = (const int*)  d_in[1];
  const float* text    = (const float*)d_in[2];
  const int*   txt_len = (const int*)  d_in[3];
  const float* Wx      = (const float*)d_in[4];
  const float* bx      = (const float*)d_in[5];
  const float* Wq      = (const float*)d_in[6];
  const float* bq      = (const float*)d_in[7];
  const float* Wout    = (const float*)d_in[8];
  const float* bout    = (const float*)d_in[9];
  const float* v       = (const float*)d_in[10];
  const float* wih     = (const float*)d_in[11];
  const float* whh     = (const float*)d_in[12];
  const float* bih     = (const float*)d_in[13];
  const float* bhh     = (const float*)d_in[14];
  const float* p1w     = (const float*)d_in[15];
  const float* p1b     = (const float*)d_in[16];
  const float* p2w     = (const float*)d_in[17];
  const float* p2b     = (const float*)d_in[18];
  float* ws  = (float*)d_ws;
  float* out = (float*)d_out;

  k_prep <<<1618, 256, 0, stream>>>(Wout, bout, v, Wx, Wq, wih, bih, bhh, ws);
  k_xq   <<<1056, 256, 0, stream>>>(x, bx, text, bq, ws);
  k_score<<<1024, 256, 0, stream>>>(mel_len, ws, out);

  float* G = ws + OFF_G;
  k_gates<<<256, 512, 0, stream>>>(ws + OFF_H0, ws + OFF_HS0, txt_len, G, 0, ws);
  k_scan <<<16, 512, 0, stream>>>(G, whh, ws + OFF_HS0, 0);
  k_gates<<<256, 512, 0, stream>>>(ws + OFF_H0, ws + OFF_HS0, txt_len, G, 1, ws);
  k_scan <<<16, 512, 0, stream>>>(G, whh, ws + OFF_HS1, 1);

  k_final<<<8, 256, 0, stream>>>(ws + OFF_HS1, txt_len, p1w, p1b, p2w, p2b, out);
}

// Round 14
// 460.972 us; speedup vs baseline: 1.3723x; 1.0608x over previous
//
#include <hip/hip_runtime.h>
#include <hip/hip_bf16.h>
#include <math.h>

#define B 8
#define T_MEL 400
#define N_MEL 80
#define L_TXT 128
#define D_TXT 512
#define E 256
#define HID 256
#define EMB 128
#define N_SPK 100
#define HH 128

// ---- workspace layout (float element offsets) ----
#define OFF_W      0
#define OFF_C      256
#define OFF_WXT    272
#define OFF_WQT    (OFF_WXT + N_MEL*E)        // 20752
#define OFF_WIHT   (OFF_WQT + D_TXT*E)        // 151824 ; now uint[4][128][512] f16-pairs (view-cast)
#define OFF_BSUM   (OFF_WIHT + 2*2*256*512)   // 676112
#define OFF_X1     (OFF_BSUM + 2048)          // 678160
#define OFF_Q1     (OFF_X1 + B*T_MEL*E)       // 1497360
#define OFF_G      OFF_X1                      // gates overlay x1+q1 (dead by then)
#define OFF_H0     (OFF_Q1 + B*L_TXT*E)       // 1759504
#define OFF_O1     (OFF_H0 + B*L_TXT*E)       // 2021648
#define OFF_HS0    OFF_H0                      // hseq layer0 overlays H0 (dead after k_gates0)
#define OFF_HS1    OFF_O1                      // hseq layer1 in O1 region

typedef _Float16 half2v __attribute__((ext_vector_type(2)));

__device__ __forceinline__ float fast_sigmoid(float x){ return 1.f/(1.f+__expf(-x)); }
__device__ __forceinline__ float fast_tanh(float x){ float e=__expf(2.f*x); return 1.f - 2.f/(e+1.f); }

__device__ __forceinline__ float fdot2(uint a, uint b, float c){
  half2v ha = __builtin_bit_cast(half2v, a);
  half2v hb = __builtin_bit_cast(half2v, b);
#if __has_builtin(__builtin_amdgcn_fdot2)
  return __builtin_amdgcn_fdot2(ha, hb, c, false);
#else
  float r;
  asm("v_dot2_f32_f16 %0, %1, %2, %3" : "=v"(r) : "v"(a), "v"(b), "v"(c));
  return r;
#endif
}
__device__ __forceinline__ uint packh2(float a, float b){
  union { _Float16 h[2]; uint u; } x;
  x.h[0] = (_Float16)a; x.h[1] = (_Float16)b; return x.u;
}

// ---- prep: w = Wout^T v, c = bout.v ; WXT, WQT transposes ; WihT f16-pair pack ; bias sums ----
// blocks: 0 | 1..80 WXT | 81..592 WQT | 593..1104 WihT-pack | 1105 BSUM  (grid 1106)
__global__ __launch_bounds__(256) void k_prep(const float* __restrict__ Wout, const float* __restrict__ bout,
                       const float* __restrict__ v,    const float* __restrict__ Wx,
                       const float* __restrict__ Wq,   const float* __restrict__ wih,
                       const float* __restrict__ bih,  const float* __restrict__ bhh,
                       float* __restrict__ ws){
  int blk = blockIdx.x, tid = threadIdx.x;
  if (blk == 0){
    float acc = 0.f;
    for (int j=0;j<E;j++) acc += Wout[j*E + tid] * v[j];
    ws[OFF_W + tid] = acc;
    if (tid==0){ float c=0.f; for(int j=0;j<E;j++) c += bout[j]*v[j]; ws[OFF_C]=c; }
  } else if (blk <= N_MEL){
    int m = blk-1;
    ws[OFF_WXT + m*E + tid] = Wx[tid*N_MEL + m];
  } else if (blk <= N_MEL + D_TXT){
    int k = blk-1-N_MEL;
    ws[OFF_WQT + k*E + tid] = Wq[tid*D_TXT + k];
  } else if (blk <= N_MEL + D_TXT + 512){
    int idx = blk-1-N_MEL-D_TXT;      // ld*128 + k2
    int ld = idx >> 7, k2 = idx & 127;
    uint* wout = (uint*)(ws + OFF_WIHT) + (size_t)idx*512;
    for (int g = tid; g < 512; g += 256){
      float a = wih[((size_t)(ld*512+g))*256 + 2*k2];
      float b = wih[((size_t)(ld*512+g))*256 + 2*k2 + 1];
      wout[g] = packh2(a, b);
    }
  } else {
    for (int i = tid; i < 2048; i += 256)
      ws[OFF_BSUM + i] = bih[i] + bhh[i];
  }
}

// ---- x1 (blk<800) | q1 (blk 800..1055) ; reads WXT/WQT written by k_prep ----
__global__ __launch_bounds__(256) void k_xq(const float* __restrict__ x,    const float* __restrict__ bx,
                                            const float* __restrict__ text, const float* __restrict__ bq,
                                            float* __restrict__ ws){
  __shared__ float sbuf[2048];
  int blk = blockIdx.x, tid = threadIdx.x;
  if (blk < 800){
    int b = blk/100; int t0 = (blk%100)*4;
    float (*sx)[4] = (float(*)[4])sbuf;
    for (int i = tid; i < N_MEL*4; i += 256){
      int m = i>>2, ii = i&3;
      sx[m][ii] = x[(b*N_MEL+m)*T_MEL + t0 + ii];
    }
    __syncthreads();
    float bxe = bx[tid];
    float a0=bxe,a1=bxe,a2=bxe,a3=bxe;
    const float* wxt = ws + OFF_WXT;
    #pragma unroll 4
    for (int m=0;m<N_MEL;m++){
      float w = wxt[m*E + tid];
      a0 += sx[m][0]*w; a1 += sx[m][1]*w; a2 += sx[m][2]*w; a3 += sx[m][3]*w;
    }
    float* x1 = ws + OFF_X1 + (b*T_MEL + t0)*E + tid;
    x1[0]=a0; x1[E]=a1; x1[2*E]=a2; x1[3*E]=a3;
  } else {
    int bb = blk - 800;
    int b = bb/32; int l0 = (bb%32)*4;
    float (*st)[D_TXT] = (float(*)[D_TXT])sbuf;
    for (int i = tid; i < 4*D_TXT; i += 256){
      int li = i / D_TXT, k = i % D_TXT;
      st[li][k] = text[(b*L_TXT + l0 + li)*D_TXT + k];
    }
    __syncthreads();
    float bqe = bq[tid];
    float a0=bqe,a1=bqe,a2=bqe,a3=bqe;
    const float* wqt = ws + OFF_WQT;
    #pragma unroll 2
    for (int k=0;k<D_TXT;k++){
      float w = wqt[k*E + tid];
      a0 += st[0][k]*w; a1 += st[1][k]*w; a2 += st[2][k]*w; a3 += st[3][k]*w;
    }
    float* q1 = ws + OFF_Q1 + (b*L_TXT + l0)*E + tid;
    q1[0]=a0; q1[E]=a1; q1[2*E]=a2; q1[3*E]=a3;
  }
}

// ---- scores + masked softmax + context + h0 ; one block per (b,l) ----
__global__ __launch_bounds__(256) void k_score(const int* __restrict__ mel_len,
                                               float* __restrict__ ws,
                                               float* __restrict__ d_out){
  int blk = blockIdx.x; int b = blk >> 7; int l = blk & 127;
  int tid = threadIdx.x; int lane = tid & 63; int wv = tid >> 6;
  __shared__ __align__(16) float sl[T_MEL];
  __shared__ float red[8];
  const float* x1 = ws + OFF_X1 + b*T_MEL*E;
  const float* q1 = ws + OFF_Q1 + (b*L_TXT+l)*E;
  int g = lane >> 4, i = lane & 15;      // group (which t), e-chunk
  float qv[16], wvv[16];
  {
    const float4* q4 = (const float4*)(q1 + i*16);
    const float4* w4 = (const float4*)(ws + OFF_W + i*16);
    #pragma unroll
    for (int j=0;j<4;j++){
      float4 a = q4[j]; qv[4*j]=a.x; qv[4*j+1]=a.y; qv[4*j+2]=a.z; qv[4*j+3]=a.w;
      float4 c = w4[j]; wvv[4*j]=c.x; wvv[4*j+1]=c.y; wvv[4*j+2]=c.z; wvv[4*j+3]=c.w;
    }
  }
  float cc = ws[OFF_C];
  int len = mel_len[b];
  #pragma unroll 2
  for (int iter=0; iter<25; iter++){
    int t = iter*16 + wv*4 + g;
    const float4* xr = (const float4*)(x1 + t*E + i*16);
    float s = 0.f;
    #pragma unroll
    for (int j=0;j<4;j++){
      float4 xv = xr[j];
      s += wvv[4*j+0]*fast_tanh(xv.x + qv[4*j+0]);
      s += wvv[4*j+1]*fast_tanh(xv.y + qv[4*j+1]);
      s += wvv[4*j+2]*fast_tanh(xv.z + qv[4*j+2]);
      s += wvv[4*j+3]*fast_tanh(xv.w + qv[4*j+3]);
    }
    s += __shfl_xor(s,1); s += __shfl_xor(s,2);
    s += __shfl_xor(s,4); s += __shfl_xor(s,8);
    if (i==0) sl[t] = s + cc;
  }
  __syncthreads();
  float mx = -3.0e38f;
  for (int t = tid; t < T_MEL; t += 256) if (t < len) mx = fmaxf(mx, sl[t]);
  #pragma unroll
  for (int off=32; off>=1; off>>=1) mx = fmaxf(mx, __shfl_xor(mx, off));
  if (lane==0) red[wv] = mx;
  __syncthreads();
  mx = fmaxf(fmaxf(red[0],red[1]),fmaxf(red[2],red[3]));
  float se = 0.f;
  for (int t = tid; t < T_MEL; t += 256){
    float p = (t < len) ? __expf(sl[t]-mx) : 0.f;
    sl[t] = p; se += p;
  }
  #pragma unroll
  for (int off=32; off>=1; off>>=1) se += __shfl_xor(se, off);
  if (lane==0) red[4+wv] = se;
  __syncthreads();
  float rsum = 1.f/(red[4]+red[5]+red[6]+red[7]);
  float* sc_out = d_out + 1824 + (b*L_TXT + l)*T_MEL;
  for (int t = tid; t < T_MEL; t += 256){
    float p = sl[t]*rsum;
    sl[t] = p; sc_out[t] = p;
  }
  __syncthreads();
  float a = 0.f;
  int e = tid;
  for (int t = 0; t < T_MEL; t += 4){
    float4 p4 = *(const float4*)&sl[t];     // sl=0 past len -> no guard needed
    a += p4.x*x1[(t  )*E+e] + p4.y*x1[(t+1)*E+e]
       + p4.z*x1[(t+2)*E+e] + p4.w*x1[(t+3)*E+e];
  }
  ws[OFF_H0 + (b*L_TXT+l)*E + e] = q1[e] + a;
}

// ---- gates v2: f16-pair packed inputs + weights, uint4 LDS reads, fdot2 MACs.
//      layer0 reads H0[b][l][256]; layer1 reads hseq0 with pack-reverse fold.
//      output: G[dir][t][b][row]  (row = gate*128+unit, PyTorch order i,f,g,o) ----
__global__ __launch_bounds__(512) void k_gates(const float* __restrict__ in,
                                               const float* __restrict__ hs,
                                               const int* __restrict__ txt_len,
                                               float* __restrict__ gates, int layer,
                                               float* __restrict__ ws){
  int idx = blockIdx.x; int tt = idx & 15; int dir = (idx>>4)&1; int b = idx>>5;
  int tid = threadIdx.x;
  __shared__ __align__(16) uint sih[8][128];   // 8 rows x 128 f16-pairs (k = 2*k2)
  int len = txt_len[b];
  for (int i = tid; i < 8*128; i += 512){
    int r = i >> 7, k2 = i & 127;
    int t = tt*8 + r;
    int row = dir ? max(0, len-1-t) : t;
    float va, vb;
    if (layer == 0){
      const float2 p = *(const float2*)&in[((size_t)(b*L_TXT + row))*HID + 2*k2];
      va = p.x; vb = p.y;
    } else {
      int k = 2*k2; int d = k >> 7, u = k & 127;   // k even -> k,k+1 share d
      int sidx = (d==0) ? row : (row < len ? len-1-row : 0);
      const float* hr = hs + (((size_t)(d*8+b)*128) + u)*128 + sidx;
      va = hr[0]; vb = hr[128];
    }
    sih[r][k2] = packh2(va, vb);
  }
  __syncthreads();
  int ld = layer*2 + dir;
  int g = tid;
  float bsum = ws[OFF_BSUM + ld*512 + g];
  float acc[8];
  #pragma unroll
  for (int r=0;r<8;r++) acc[r] = bsum;
  const uint* wt2 = (const uint*)(ws + OFF_WIHT) + (size_t)ld*128*512 + g;
  for (int k4=0; k4<128; k4+=4){
    uint w0 = wt2[(k4  )*512];
    uint w1 = wt2[(k4+1)*512];
    uint w2 = wt2[(k4+2)*512];
    uint w3 = wt2[(k4+3)*512];
    #pragma unroll
    for (int r=0;r<8;r++){
      uint4 s4 = *(const uint4*)&sih[r][k4];
      acc[r] = fdot2(s4.x, w0, acc[r]);
      acc[r] = fdot2(s4.y, w1, acc[r]);
      acc[r] = fdot2(s4.z, w2, acc[r]);
      acc[r] = fdot2(s4.w, w3, acc[r]);
    }
  }
  float* go = gates + (((size_t)(dir*L_TXT + tt*8)*8) + b)*512 + g;
  #pragma unroll
  for (int r=0;r<8;r++) go[(size_t)r*8*512] = acc[r];
}

// ---- recurrent scan v12: v11 + 4-way split fdot2 chains (critical path) ----
__global__ __launch_bounds__(512) void k_scan(const float* __restrict__ Gp,
                                              const float* __restrict__ whh_all,
                                              float* __restrict__ hseq, int layer){
  int dir = blockIdx.x & 1; int b = blockIdx.x >> 1;
  int tid = threadIdx.x;
  int l = tid & 63, w = tid >> 6;
  int gt = l >> 4;           // 0:i 1:f 2:g 3:o
  int li = l & 15;
  int u  = w*16 + li;        // unit 0..127
  int row = gt*128 + u;      // gate row

  __shared__ uint wlds[32768];      // 128KB f16 pairs: [w][phase j][lane][4]
  __shared__ uint h2buf[2][64];     // rolling h as half2

  const float* wr = whh_all + ((size_t)((layer*2+dir)*512 + row))*HH;
  #pragma unroll
  for (int j=0;j<16;j++){
    uint4 vv;
    vv.x = packh2(wr[j*8+0], wr[j*8+1]);
    vv.y = packh2(wr[j*8+2], wr[j*8+3]);
    vv.z = packh2(wr[j*8+4], wr[j*8+5]);
    vv.w = packh2(wr[j*8+6], wr[j*8+7]);
    *(uint4*)(wlds + w*4096 + j*256 + l*4) = vv;
  }
  if (tid < 128) ((uint*)h2buf)[tid] = 0;

  const float* gb = Gp + ((size_t)(dir*L_TXT)*8 + b)*512 + row;
  float gi = gb[0];
  float c_reg = 0.f;
  float hm1=0.f, hm2=0.f, hm3=0.f;
  bool isg = (gt==2);
  __syncthreads();

  const uint4* wp = (const uint4*)(wlds + w*4096 + l*4);   // phase j at wp[j*64]
  float* hout = hseq + (((size_t)(dir*8+b)*128) + u)*128;

  for (int s=0; s<L_TXT; s++){
    float gnext = gb[(size_t)(s+1 < L_TXT ? s+1 : s)*4096];
    const uint4* hp = (const uint4*)(h2buf[s&1]);          // broadcast reads
    float p0 = gi, p1 = 0.f, p2 = 0.f, p3 = 0.f;           // 4 independent chains
    #pragma unroll
    for (int j=0;j<16;j+=4){
      uint4 A0 = wp[(j  )*64], H0 = hp[j  ];
      uint4 A1 = wp[(j+1)*64], H1 = hp[j+1];
      uint4 A2 = wp[(j+2)*64], H2 = hp[j+2];
      uint4 A3 = wp[(j+3)*64], H3 = hp[j+3];
      p0 = fdot2(A0.x,H0.x,p0); p0 = fdot2(A0.y,H0.y,p0);
      p0 = fdot2(A0.z,H0.z,p0); p0 = fdot2(A0.w,H0.w,p0);
      p1 = fdot2(A1.x,H1.x,p1); p1 = fdot2(A1.y,H1.y,p1);
      p1 = fdot2(A1.z,H1.z,p1); p1 = fdot2(A1.w,H1.w,p1);
      p2 = fdot2(A2.x,H2.x,p2); p2 = fdot2(A2.y,H2.y,p2);
      p2 = fdot2(A2.z,H2.z,p2); p2 = fdot2(A2.w,H2.w,p2);
      p3 = fdot2(A3.x,H3.x,p3); p3 = fdot2(A3.y,H3.y,p3);
      p3 = fdot2(A3.z,H3.z,p3); p3 = fdot2(A3.w,H3.w,p3);
    }
    float acc = (p0+p1)+(p2+p3);
    float xa = isg ? 2.f*acc : acc;
    float sg = 1.f/(1.f+__expf(-xa));
    float val = isg ? 2.f*sg - 1.f : sg;
    float x  = __shfl_xor(val, 16);
    float y0 = __shfl_xor(val, 32);
    float y1 = __shfl_xor(x,   32);
    float iv = (gt==0)?val : (gt==1)?x  : (gt==2)?y0 : y1;
    float fv = (gt==0)?x   : (gt==1)?val: (gt==2)?y1 : y0;
    float gv = (gt==0)?y0  : (gt==1)?y1 : (gt==2)?val: x;
    float ov = (gt==0)?y1  : (gt==1)?y0 : (gt==2)?x  : val;
    c_reg = fv*c_reg + iv*gv;
    float h = ov*fast_tanh(c_reg);
    float hn = __shfl_xor(h, 1);
    if (gt==0 && !(li&1)) h2buf[(s+1)&1][u>>1] = packh2(h, hn);
    if (gt==0 && (s&3)==3)
      *(float4*)&hout[s-3] = make_float4(hm3, hm2, hm1, h);
    hm3 = hm2; hm2 = hm1; hm1 = h;
    gi = gnext;
    __syncthreads();
  }
}

// ---- masked mean pool (direct from hseq1, float4) + p1/tanh + normalize + p2 ----
__global__ __launch_bounds__(256) void k_final(const float* __restrict__ hs,
                                               const int* __restrict__ txt_len,
                                               const float* __restrict__ p1w,
                                               const float* __restrict__ p1b,
                                               const float* __restrict__ p2w,
                                               const float* __restrict__ p2b,
                                               float* __restrict__ d_out){
  int b = blockIdx.x; int tid = threadIdx.x;
  __shared__ float pl[HID];
  __shared__ float ol[EMB];
  __shared__ float nrm;
  int len = txt_len[b];
  int d = tid >> 7, u = tid & 127;
  const float* hrow = hs + (((size_t)(d*8+b)*128) + u)*128;
  float s = 0.f;
  int t4 = len & ~3;
  for (int t=0; t<t4; t+=4){
    float4 p = *(const float4*)&hrow[t];
    s += (p.x + p.y) + (p.z + p.w);
  }
  for (int t=t4; t<len; t++) s += hrow[t];
  pl[tid] = s / (float)len;
  __syncthreads();
  if (tid < EMB){
    float a = p1b[tid];
    for (int k=0;k<HID;k++) a += pl[k]*p1w[tid*HID+k];
    ol[tid] = fast_tanh(a);
  }
  __syncthreads();
  if (tid == 0){
    float q = 0.f;
    for (int k=0;k<EMB;k++) q += ol[k]*ol[k];
    nrm = rsqrtf(q);
  }
  __syncthreads();
  if (tid < EMB) d_out[800 + b*EMB + tid] = ol[tid]*nrm;
  if (tid < N_SPK){
    float a = p2b[tid];
    for (int k=0;k<EMB;k++) a += ol[k]*p2w[tid*EMB+k];
    d_out[b*N_SPK + tid] = a;
  }
}

extern "C" void kernel_launch(void* const* d_in, const int* in_sizes, int n_in,
                              void* d_out, int out_size, void* d_ws, size_t ws_size,
                              hipStream_t stream) {
  const float* x       = (const float*)d_in[0];
  const int*   mel_len = (const int*)  d_in[1];
  const float* text    = (const float*)d_in[2];
  const int*   txt_len = (const int*)  d_in[3];
  const float* Wx      = (const float*)d_in[4];
  const float* bx      = (const float*)d_in[5];
  const float* Wq      = (const float*)d_in[6];
  const float* bq      = (const float*)d_in[7];
  const float* Wout    = (const float*)d_in[8];
  const float* bout    = (const float*)d_in[9];
  const float* v       = (const float*)d_in[10];
  const float* wih     = (const float*)d_in[11];
  const float* whh     = (const float*)d_in[12];
  const float* bih     = (const float*)d_in[13];
  const float* bhh     = (const float*)d_in[14];
  const float* p1w     = (const float*)d_in[15];
  const float* p1b     = (const float*)d_in[16];
  const float* p2w     = (const float*)d_in[17];
  const float* p2b     = (const float*)d_in[18];
  float* ws  = (float*)d_ws;
  float* out = (float*)d_out;

  k_prep <<<1106, 256, 0, stream>>>(Wout, bout, v, Wx, Wq, wih, bih, bhh, ws);
  k_xq   <<<1056, 256, 0, stream>>>(x, bx, text, bq, ws);
  k_score<<<1024, 256, 0, stream>>>(mel_len, ws, out);

  float* G = ws + OFF_G;
  k_gates<<<256, 512, 0, stream>>>(ws + OFF_H0, ws + OFF_HS0, txt_len, G, 0, ws);
  k_scan <<<16, 512, 0, stream>>>(G, whh, ws + OFF_HS0, 0);
  k_gates<<<256, 512, 0, stream>>>(ws + OFF_H0, ws + OFF_HS0, txt_len, G, 1, ws);
  k_scan <<<16, 512, 0, stream>>>(G, whh, ws + OFF_HS1, 1);

  k_final<<<8, 256, 0, stream>>>(ws + OFF_HS1, txt_len, p1w, p1b, p2w, p2b, out);
}

// Round 16
// 453.457 us; speedup vs baseline: 1.3950x; 1.0166x over previous
//
#include <hip/hip_runtime.h>
#include <hip/hip_bf16.h>
#include <math.h>

#define B 8
#define T_MEL 400
#define N_MEL 80
#define L_TXT 128
#define D_TXT 512
#define E 256
#define HID 256
#define EMB 128
#define N_SPK 100
#define HH 128

// ---- workspace layout (float element offsets) ----
#define OFF_W      0
#define OFF_C      256
#define OFF_WXT    272
#define OFF_WQT    (OFF_WXT + N_MEL*E)        // 20752
#define OFF_WIHT   (OFF_WQT + D_TXT*E)        // 151824 ; uint[4][128][512] f16-pairs (view-cast)
#define OFF_BSUM   (OFF_WIHT + 2*2*256*512)   // 676112
#define OFF_X1     (OFF_BSUM + 2048)          // 678160
#define OFF_Q1     (OFF_X1 + B*T_MEL*E)       // 1497360
#define OFF_G      OFF_X1                      // gates overlay x1+q1 (dead by then)
#define OFF_H0     (OFF_Q1 + B*L_TXT*E)       // 1759504
#define OFF_O1     (OFF_H0 + B*L_TXT*E)       // 2021648
#define OFF_HS0    OFF_H0                      // hseq layer0 overlays H0 (dead after k_gates0)
#define OFF_POOL   OFF_O1                      // pooled[2][8][128] floats (written by scan L1)

typedef _Float16 half2v __attribute__((ext_vector_type(2)));

__device__ __forceinline__ float fast_sigmoid(float x){ return 1.f/(1.f+__expf(-x)); }
__device__ __forceinline__ float fast_tanh(float x){ float e=__expf(2.f*x); return 1.f - 2.f/(e+1.f); }

__device__ __forceinline__ float fdot2(uint a, uint b, float c){
  half2v ha = __builtin_bit_cast(half2v, a);
  half2v hb = __builtin_bit_cast(half2v, b);
#if __has_builtin(__builtin_amdgcn_fdot2)
  return __builtin_amdgcn_fdot2(ha, hb, c, false);
#else
  float r;
  asm("v_dot2_f32_f16 %0, %1, %2, %3" : "=v"(r) : "v"(a), "v"(b), "v"(c));
  return r;
#endif
}
__device__ __forceinline__ uint packh2(float a, float b){
  union { _Float16 h[2]; uint u; } x;
  x.h[0] = (_Float16)a; x.h[1] = (_Float16)b; return x.u;
}

// ---- prep: w = Wout^T v, c = bout.v ; WXT, WQT transposes ; WihT f16-pair pack ; bias sums ----
__global__ __launch_bounds__(256) void k_prep(const float* __restrict__ Wout, const float* __restrict__ bout,
                       const float* __restrict__ v,    const float* __restrict__ Wx,
                       const float* __restrict__ Wq,   const float* __restrict__ wih,
                       const float* __restrict__ bih,  const float* __restrict__ bhh,
                       float* __restrict__ ws){
  int blk = blockIdx.x, tid = threadIdx.x;
  if (blk == 0){
    float acc = 0.f;
    for (int j=0;j<E;j++) acc += Wout[j*E + tid] * v[j];
    ws[OFF_W + tid] = acc;
    if (tid==0){ float c=0.f; for(int j=0;j<E;j++) c += bout[j]*v[j]; ws[OFF_C]=c; }
  } else if (blk <= N_MEL){
    int m = blk-1;
    ws[OFF_WXT + m*E + tid] = Wx[tid*N_MEL + m];
  } else if (blk <= N_MEL + D_TXT){
    int k = blk-1-N_MEL;
    ws[OFF_WQT + k*E + tid] = Wq[tid*D_TXT + k];
  } else if (blk <= N_MEL + D_TXT + 512){
    int idx = blk-1-N_MEL-D_TXT;      // ld*128 + k2
    int ld = idx >> 7, k2 = idx & 127;
    uint* wout = (uint*)(ws + OFF_WIHT) + (size_t)idx*512;
    for (int g = tid; g < 512; g += 256){
      float a = wih[((size_t)(ld*512+g))*256 + 2*k2];
      float b = wih[((size_t)(ld*512+g))*256 + 2*k2 + 1];
      wout[g] = packh2(a, b);
    }
  } else {
    for (int i = tid; i < 2048; i += 256)
      ws[OFF_BSUM + i] = bih[i] + bhh[i];
  }
}

// ---- x1 (blk<800) | q1 (blk 800..1055) ; reads WXT/WQT written by k_prep ----
__global__ __launch_bounds__(256) void k_xq(const float* __restrict__ x,    const float* __restrict__ bx,
                                            const float* __restrict__ text, const float* __restrict__ bq,
                                            float* __restrict__ ws){
  __shared__ float sbuf[2048];
  int blk = blockIdx.x, tid = threadIdx.x;
  if (blk < 800){
    int b = blk/100; int t0 = (blk%100)*4;
    float (*sx)[4] = (float(*)[4])sbuf;
    for (int i = tid; i < N_MEL*4; i += 256){
      int m = i>>2, ii = i&3;
      sx[m][ii] = x[(b*N_MEL+m)*T_MEL + t0 + ii];
    }
    __syncthreads();
    float bxe = bx[tid];
    float a0=bxe,a1=bxe,a2=bxe,a3=bxe;
    const float* wxt = ws + OFF_WXT;
    #pragma unroll 4
    for (int m=0;m<N_MEL;m++){
      float w = wxt[m*E + tid];
      a0 += sx[m][0]*w; a1 += sx[m][1]*w; a2 += sx[m][2]*w; a3 += sx[m][3]*w;
    }
    float* x1 = ws + OFF_X1 + (b*T_MEL + t0)*E + tid;
    x1[0]=a0; x1[E]=a1; x1[2*E]=a2; x1[3*E]=a3;
  } else {
    int bb = blk - 800;
    int b = bb/32; int l0 = (bb%32)*4;
    float (*st)[D_TXT] = (float(*)[D_TXT])sbuf;
    for (int i = tid; i < 4*D_TXT; i += 256){
      int li = i / D_TXT, k = i % D_TXT;
      st[li][k] = text[(b*L_TXT + l0 + li)*D_TXT + k];
    }
    __syncthreads();
    float bqe = bq[tid];
    float a0=bqe,a1=bqe,a2=bqe,a3=bqe;
    const float* wqt = ws + OFF_WQT;
    #pragma unroll 2
    for (int k=0;k<D_TXT;k++){
      float w = wqt[k*E + tid];
      a0 += st[0][k]*w; a1 += st[1][k]*w; a2 += st[2][k]*w; a3 += st[3][k]*w;
    }
    float* q1 = ws + OFF_Q1 + (b*L_TXT + l0)*E + tid;
    q1[0]=a0; q1[E]=a1; q1[2*E]=a2; q1[3*E]=a3;
  }
}

// ---- scores + masked softmax + context + h0 ; one block per (b,l) ----
__global__ __launch_bounds__(256) void k_score(const int* __restrict__ mel_len,
                                               float* __restrict__ ws,
                                               float* __restrict__ d_out){
  int blk = blockIdx.x; int b = blk >> 7; int l = blk & 127;
  int tid = threadIdx.x; int lane = tid & 63; int wv = tid >> 6;
  __shared__ __align__(16) float sl[T_MEL];
  __shared__ float red[8];
  const float* x1 = ws + OFF_X1 + b*T_MEL*E;
  const float* q1 = ws + OFF_Q1 + (b*L_TXT+l)*E;
  int g = lane >> 4, i = lane & 15;      // group (which t), e-chunk
  float qv[16], wvv[16];
  {
    const float4* q4 = (const float4*)(q1 + i*16);
    const float4* w4 = (const float4*)(ws + OFF_W + i*16);
    #pragma unroll
    for (int j=0;j<4;j++){
      float4 a = q4[j]; qv[4*j]=a.x; qv[4*j+1]=a.y; qv[4*j+2]=a.z; qv[4*j+3]=a.w;
      float4 c = w4[j]; wvv[4*j]=c.x; wvv[4*j+1]=c.y; wvv[4*j+2]=c.z; wvv[4*j+3]=c.w;
    }
  }
  float cc = ws[OFF_C];
  int len = mel_len[b];
  #pragma unroll 2
  for (int iter=0; iter<25; iter++){
    int t = iter*16 + wv*4 + g;
    const float4* xr = (const float4*)(x1 + t*E + i*16);
    float s = 0.f;
    #pragma unroll
    for (int j=0;j<4;j++){
      float4 xv = xr[j];
      s += wvv[4*j+0]*fast_tanh(xv.x + qv[4*j+0]);
      s += wvv[4*j+1]*fast_tanh(xv.y + qv[4*j+1]);
      s += wvv[4*j+2]*fast_tanh(xv.z + qv[4*j+2]);
      s += wvv[4*j+3]*fast_tanh(xv.w + qv[4*j+3]);
    }
    s += __shfl_xor(s,1); s += __shfl_xor(s,2);
    s += __shfl_xor(s,4); s += __shfl_xor(s,8);
    if (i==0) sl[t] = s + cc;
  }
  __syncthreads();
  float mx = -3.0e38f;
  for (int t = tid; t < T_MEL; t += 256) if (t < len) mx = fmaxf(mx, sl[t]);
  #pragma unroll
  for (int off=32; off>=1; off>>=1) mx = fmaxf(mx, __shfl_xor(mx, off));
  if (lane==0) red[wv] = mx;
  __syncthreads();
  mx = fmaxf(fmaxf(red[0],red[1]),fmaxf(red[2],red[3]));
  float se = 0.f;
  for (int t = tid; t < T_MEL; t += 256){
    float p = (t < len) ? __expf(sl[t]-mx) : 0.f;
    sl[t] = p; se += p;
  }
  #pragma unroll
  for (int off=32; off>=1; off>>=1) se += __shfl_xor(se, off);
  if (lane==0) red[4+wv] = se;
  __syncthreads();
  float rsum = 1.f/(red[4]+red[5]+red[6]+red[7]);
  float* sc_out = d_out + 1824 + (b*L_TXT + l)*T_MEL;
  for (int t = tid; t < T_MEL; t += 256){
    float p = sl[t]*rsum;
    sl[t] = p; sc_out[t] = p;
  }
  __syncthreads();
  float a = 0.f;
  int e = tid;
  for (int t = 0; t < T_MEL; t += 4){
    float4 p4 = *(const float4*)&sl[t];     // sl=0 past len -> no guard needed
    a += p4.x*x1[(t  )*E+e] + p4.y*x1[(t+1)*E+e]
       + p4.z*x1[(t+2)*E+e] + p4.w*x1[(t+3)*E+e];
  }
  ws[OFF_H0 + (b*L_TXT+l)*E + e] = q1[e] + a;
}

// ---- gates v2: f16-pair packed inputs + weights, uint4 LDS reads, fdot2 MACs.
//      layer0 reads H0[b][l][256]; layer1 reads hseq0 with pack-reverse fold.
//      output: G[dir][t][b][row]  (row = gate*128+unit, PyTorch order i,f,g,o) ----
__global__ __launch_bounds__(512) void k_gates(const float* __restrict__ in,
                                               const float* __restrict__ hs,
                                               const int* __restrict__ txt_len,
                                               float* __restrict__ gates, int layer,
                                               float* __restrict__ ws){
  int idx = blockIdx.x; int tt = idx & 15; int dir = (idx>>4)&1; int b = idx>>5;
  int tid = threadIdx.x;
  __shared__ __align__(16) uint sih[8][128];   // 8 rows x 128 f16-pairs (k = 2*k2)
  int len = txt_len[b];
  for (int i = tid; i < 8*128; i += 512){
    int r = i >> 7, k2 = i & 127;
    int t = tt*8 + r;
    int row = dir ? max(0, len-1-t) : t;
    float va, vb;
    if (layer == 0){
      const float2 p = *(const float2*)&in[((size_t)(b*L_TXT + row))*HID + 2*k2];
      va = p.x; vb = p.y;
    } else {
      int k = 2*k2; int d = k >> 7, u = k & 127;   // k even -> k,k+1 share d
      int sidx = (d==0) ? row : (row < len ? len-1-row : 0);
      const float* hr = hs + (((size_t)(d*8+b)*128) + u)*128 + sidx;
      va = hr[0]; vb = hr[128];
    }
    sih[r][k2] = packh2(va, vb);
  }
  __syncthreads();
  int ld = layer*2 + dir;
  int g = tid;
  float bsum = ws[OFF_BSUM + ld*512 + g];
  float acc[8];
  #pragma unroll
  for (int r=0;r<8;r++) acc[r] = bsum;
  const uint* wt2 = (const uint*)(ws + OFF_WIHT) + (size_t)ld*128*512 + g;
  for (int k4=0; k4<128; k4+=4){
    uint w0 = wt2[(k4  )*512];
    uint w1 = wt2[(k4+1)*512];
    uint w2 = wt2[(k4+2)*512];
    uint w3 = wt2[(k4+3)*512];
    #pragma unroll
    for (int r=0;r<8;r++){
      uint4 s4 = *(const uint4*)&sih[r][k4];
      acc[r] = fdot2(s4.x, w0, acc[r]);
      acc[r] = fdot2(s4.y, w1, acc[r]);
      acc[r] = fdot2(s4.z, w2, acc[r]);
      acc[r] = fdot2(s4.w, w3, acc[r]);
    }
  }
  float* go = gates + (((size_t)(dir*L_TXT + tt*8)*8) + b)*512 + g;
  #pragma unroll
  for (int r=0;r<8;r++) go[(size_t)r*8*512] = acc[r];
}

// ---- recurrent scan v13b ----
// one block per (b,dir); 256 thr = 4 waves. Thread (u=tid>>1, hf=tid&1) owns ALL
// FOUR gate rows {u,128+u,256+u,384+u} x half of h. Per step/thread: 32 weight
// b128 (128KB floor) + 8 broadcast h b128 (each feeds 4 rows) + 4 join shfl +
// 1 pair shfl => ~180 DS wave-instrs/step (v11 was ~304). No gate exchange.
// FIX vs v13: gate input counted ONCE (hf==0 lane only) before the half-join.
// layer1 fuses masked mean pool (psum in-register -> pooled[d][b][u]).
__global__ __launch_bounds__(256) void k_scan(const float* __restrict__ Gp,
                                              const float* __restrict__ whh_all,
                                              const int* __restrict__ txt_len,
                                              float* __restrict__ hseq,
                                              float* __restrict__ pooled, int layer){
  int dir = blockIdx.x & 1; int b = blockIdx.x >> 1;
  int tid = threadIdx.x;
  int l = tid & 63, w = tid >> 6;   // 4 waves
  int u  = tid >> 1;                // unit 0..127
  int hf = tid & 1;                 // half of h

  __shared__ uint wlds[32768];      // 128KB: [w][slot j=r*8+jj][lane][4]
  __shared__ uint h2buf[2][64];     // rolling h as half2

  const float* wbase = whh_all + (size_t)(layer*2+dir)*512*HH;
  #pragma unroll
  for (int r=0;r<4;r++){
    const float* wr = wbase + (size_t)(r*128+u)*HH + 64*hf;
    #pragma unroll
    for (int jj=0;jj<8;jj++){
      uint4 vv;
      vv.x = packh2(wr[jj*8+0], wr[jj*8+1]);
      vv.y = packh2(wr[jj*8+2], wr[jj*8+3]);
      vv.z = packh2(wr[jj*8+4], wr[jj*8+5]);
      vv.w = packh2(wr[jj*8+6], wr[jj*8+7]);
      *(uint4*)(wlds + w*8192 + (r*8+jj)*256 + l*4) = vv;
    }
  }
  if (tid < 128) ((uint*)h2buf)[tid] = 0;
  int len = txt_len[b];
  bool pool = (layer == 1);

  const float* gb = Gp + ((size_t)(dir*L_TXT)*8 + b)*512 + u;
  float g0 = gb[0], g1 = gb[128], g2 = gb[256], g3 = gb[384];
  float c_reg = 0.f, psum = 0.f;
  float hm1=0.f, hm2=0.f, hm3=0.f;
  __syncthreads();

  const uint4* wp = (const uint4*)(wlds + w*8192 + l*4);   // slot j at wp[j*64]
  float* hout = hseq + (((size_t)(dir*8+b)*128) + u)*128;

  for (int s=0; s<L_TXT; s++){
    const float* gn = gb + (size_t)(s+1 < L_TXT ? s+1 : s)*4096;
    float n0 = gn[0], n1 = gn[128], n2 = gn[256], n3 = gn[384];
    const uint4* hp = (const uint4*)(h2buf[s&1] + hf*32);  // 2 addrs/wave: broadcast
    // gate input counted ONCE: only the hf==0 lane seeds it (join sums both halves)
    float a0 = hf ? 0.f : g0;
    float a1 = hf ? 0.f : g1;
    float a2 = hf ? 0.f : g2;
    float a3 = hf ? 0.f : g3;
    #pragma unroll
    for (int jj=0;jj<8;jj++){
      uint4 hv = hp[jj];
      uint4 w0 = wp[(jj   )*64];
      uint4 w1 = wp[( 8+jj)*64];
      uint4 w2 = wp[(16+jj)*64];
      uint4 w3 = wp[(24+jj)*64];
      a0 = fdot2(w0.x,hv.x,a0); a0 = fdot2(w0.y,hv.y,a0);
      a0 = fdot2(w0.z,hv.z,a0); a0 = fdot2(w0.w,hv.w,a0);
      a1 = fdot2(w1.x,hv.x,a1); a1 = fdot2(w1.y,hv.y,a1);
      a1 = fdot2(w1.z,hv.z,a1); a1 = fdot2(w1.w,hv.w,a1);
      a2 = fdot2(w2.x,hv.x,a2); a2 = fdot2(w2.y,hv.y,a2);
      a2 = fdot2(w2.z,hv.z,a2); a2 = fdot2(w2.w,hv.w,a2);
      a3 = fdot2(w3.x,hv.x,a3); a3 = fdot2(w3.y,hv.y,a3);
      a3 = fdot2(w3.z,hv.z,a3); a3 = fdot2(w3.w,hv.w,a3);
    }
    a0 += __shfl_xor(a0, 1);   // join h-halves (tid^1 = same u, other hf)
    a1 += __shfl_xor(a1, 1);
    a2 += __shfl_xor(a2, 1);
    a3 += __shfl_xor(a3, 1);
    float i_ = fast_sigmoid(a0);
    float f_ = fast_sigmoid(a1);
    float g_ = fast_tanh   (a2);
    float o_ = fast_sigmoid(a3);
    c_reg = f_*c_reg + i_*g_;
    float h = o_*fast_tanh(c_reg);
    float hn = __shfl_xor(h, 2);           // unit u^1's h (same hf)
    if (hf==0 && !(u&1)) h2buf[(s+1)&1][u>>1] = packh2(h, hn);
    if (pool){
      if (s < len) psum += h;
    } else {
      if (hf==0 && (s&3)==3)
        *(float4*)&hout[s-3] = make_float4(hm3, hm2, hm1, h);
      hm3 = hm2; hm2 = hm1; hm1 = h;
    }
    g0 = n0; g1 = n1; g2 = n2; g3 = n3;
    __syncthreads();
  }
  if (pool && hf==0) pooled[((size_t)(dir*8+b))*128 + u] = psum;
}

// ---- p1/tanh + normalize + p2 ; pooling read from pooled[] (scan L1 fused it) ----
__global__ __launch_bounds__(256) void k_final(const float* __restrict__ pooled,
                                               const int* __restrict__ txt_len,
                                               const float* __restrict__ p1w,
                                               const float* __restrict__ p1b,
                                               const float* __restrict__ p2w,
                                               const float* __restrict__ p2b,
                                               float* __restrict__ d_out){
  int b = blockIdx.x; int tid = threadIdx.x;
  __shared__ float pl[HID];
  __shared__ float ol[EMB];
  __shared__ float nrm;
  int len = txt_len[b];
  int d = tid >> 7, u = tid & 127;
  pl[tid] = pooled[((size_t)(d*8+b))*128 + u] / (float)len;
  __syncthreads();
  if (tid < EMB){
    float a = p1b[tid];
    for (int k=0;k<HID;k++) a += pl[k]*p1w[tid*HID+k];
    ol[tid] = fast_tanh(a);
  }
  __syncthreads();
  if (tid == 0){
    float q = 0.f;
    for (int k=0;k<EMB;k++) q += ol[k]*ol[k];
    nrm = rsqrtf(q);
  }
  __syncthreads();
  if (tid < EMB) d_out[800 + b*EMB + tid] = ol[tid]*nrm;
  if (tid < N_SPK){
    float a = p2b[tid];
    for (int k=0;k<EMB;k++) a += ol[k]*p2w[tid*EMB+k];
    d_out[b*N_SPK + tid] = a;
  }
}

extern "C" void kernel_launch(void* const* d_in, const int* in_sizes, int n_in,
                              void* d_out, int out_size, void* d_ws, size_t ws_size,
                              hipStream_t stream) {
  const float* x       = (const float*)d_in[0];
  const int*   mel_len = (const int*)  d_in[1];
  const float* text    = (const float*)d_in[2];
  const int*   txt_len = (const int*)  d_in[3];
  const float* Wx      = (const float*)d_in[4];
  const float* bx      = (const float*)d_in[5];
  const float* Wq      = (const float*)d_in[6];
  const float* bq      = (const float*)d_in[7];
  const float* Wout    = (const float*)d_in[8];
  const float* bout    = (const float*)d_in[9];
  const float* v       = (const float*)d_in[10];
  const float* wih     = (const float*)d_in[11];
  const float* whh     = (const float*)d_in[12];
  const float* bih     = (const float*)d_in[13];
  const float* bhh     = (const float*)d_in[14];
  const float* p1w     = (const float*)d_in[15];
  const float* p1b     = (const float*)d_in[16];
  const float* p2w     = (const float*)d_in[17];
  const float* p2b     = (const float*)d_in[18];
  float* ws  = (float*)d_ws;
  float* out = (float*)d_out;

  k_prep <<<1106, 256, 0, stream>>>(Wout, bout, v, Wx, Wq, wih, bih, bhh, ws);
  k_xq   <<<1056, 256, 0, stream>>>(x, bx, text, bq, ws);
  k_score<<<1024, 256, 0, stream>>>(mel_len, ws, out);

  float* G = ws + OFF_G;
  k_gates<<<256, 512, 0, stream>>>(ws + OFF_H0, ws + OFF_HS0, txt_len, G, 0, ws);
  k_scan <<<16, 256, 0, stream>>>(G, whh, txt_len, ws + OFF_HS0, ws + OFF_POOL, 0);
  k_gates<<<256, 512, 0, stream>>>(ws + OFF_H0, ws + OFF_HS0, txt_len, G, 1, ws);
  k_scan <<<16, 256, 0, stream>>>(G, whh, txt_len, ws + OFF_HS0, ws + OFF_POOL, 1);

  k_final<<<8, 256, 0, stream>>>(ws + OFF_POOL, txt_len, p1w, p1b, p2w, p2b, out);
}

// Round 17
// 429.399 us; speedup vs baseline: 1.4732x; 1.0560x over previous
//
#include <hip/hip_runtime.h>
#include <hip/hip_bf16.h>
#include <math.h>

#define B 8
#define T_MEL 400
#define N_MEL 80
#define L_TXT 128
#define D_TXT 512
#define E 256
#define HID 256
#define EMB 128
#define N_SPK 100
#define HH 128

// ---- workspace layout (float element offsets) ----
#define OFF_W      0
#define OFF_C      256
#define OFF_WXT    272
#define OFF_WQT    (OFF_WXT + N_MEL*E)        // 20752
#define OFF_WIHT   (OFF_WQT + D_TXT*E)        // 151824 ; uint[4][128][512] f16-pairs (view-cast)
#define OFF_BSUM   (OFF_WIHT + 2*2*256*512)   // 676112
#define OFF_X1     (OFF_BSUM + 2048)          // 678160
#define OFF_Q1     (OFF_X1 + B*T_MEL*E)       // 1497360
#define OFF_G      OFF_X1                      // gates overlay x1+q1 (dead by then)
#define OFF_H0     (OFF_Q1 + B*L_TXT*E)       // 1759504
#define OFF_O1     (OFF_H0 + B*L_TXT*E)       // 2021648
#define OFF_HS0    OFF_H0                      // hseq layer0 overlays H0 (dead after k_gates0)
#define OFF_POOL   OFF_O1                      // pooled[2][8][128] floats (written by scan L1)
#define OFF_WG     (OFF_O1 + 4096)            // 2025744 ; uint[4][4][8192] Whh f16-pairs, wave-contig

typedef _Float16 half2v __attribute__((ext_vector_type(2)));

__device__ __forceinline__ float fast_sigmoid(float x){ return 1.f/(1.f+__expf(-x)); }
__device__ __forceinline__ float fast_tanh(float x){ float e=__expf(2.f*x); return 1.f - 2.f/(e+1.f); }

__device__ __forceinline__ float fdot2(uint a, uint b, float c){
  half2v ha = __builtin_bit_cast(half2v, a);
  half2v hb = __builtin_bit_cast(half2v, b);
#if __has_builtin(__builtin_amdgcn_fdot2)
  return __builtin_amdgcn_fdot2(ha, hb, c, false);
#else
  float r;
  asm("v_dot2_f32_f16 %0, %1, %2, %3" : "=v"(r) : "v"(a), "v"(b), "v"(c));
  return r;
#endif
}
__device__ __forceinline__ uint packh2(float a, float b){
  union { _Float16 h[2]; uint u; } x;
  x.h[0] = (_Float16)a; x.h[1] = (_Float16)b; return x.u;
}

// ---- prep: w/c, WXT, WQT, WihT f16 pack, BSUM, + Whh global f16 pack (wave-contig) ----
// blocks: 0 | 1..80 WXT | 81..592 WQT | 593..1104 WihT | 1105 BSUM | 1106..1121 WhhG
__global__ __launch_bounds__(256) void k_prep(const float* __restrict__ Wout, const float* __restrict__ bout,
                       const float* __restrict__ v,    const float* __restrict__ Wx,
                       const float* __restrict__ Wq,   const float* __restrict__ wih,
                       const float* __restrict__ bih,  const float* __restrict__ bhh,
                       const float* __restrict__ whh,  float* __restrict__ ws){
  int blk = blockIdx.x, tid = threadIdx.x;
  if (blk == 0){
    float acc = 0.f;
    for (int j=0;j<E;j++) acc += Wout[j*E + tid] * v[j];
    ws[OFF_W + tid] = acc;
    if (tid==0){ float c=0.f; for(int j=0;j<E;j++) c += bout[j]*v[j]; ws[OFF_C]=c; }
  } else if (blk <= N_MEL){
    int m = blk-1;
    ws[OFF_WXT + m*E + tid] = Wx[tid*N_MEL + m];
  } else if (blk <= N_MEL + D_TXT){
    int k = blk-1-N_MEL;
    ws[OFF_WQT + k*E + tid] = Wq[tid*D_TXT + k];
  } else if (blk <= N_MEL + D_TXT + 512){
    int idx = blk-1-N_MEL-D_TXT;      // ld*128 + k2
    int ld = idx >> 7, k2 = idx & 127;
    uint* wout = (uint*)(ws + OFF_WIHT) + (size_t)idx*512;
    for (int g = tid; g < 512; g += 256){
      float a = wih[((size_t)(ld*512+g))*256 + 2*k2];
      float b = wih[((size_t)(ld*512+g))*256 + 2*k2 + 1];
      wout[g] = packh2(a, b);
    }
  } else if (blk == 1105){
    for (int i = tid; i < 2048; i += 256)
      ws[OFF_BSUM + i] = bih[i] + bhh[i];
  } else {
    // pack Whh -> WG[ld][w][ (r*8+jj)*256 + l*4 + k ] matching scan's wlds formula
    int bp = blk - 1106;            // 0..15
    int ld = bp >> 2, w = bp & 3;
    uint* wg = (uint*)(ws + OFF_WG) + ((size_t)ld*4 + w)*8192;
    for (int ii = 0; ii < 32; ii++){
      int i = ii*256 + tid;         // 0..8191
      int r  = i >> 11;
      int jj = (i >> 8) & 7;
      int l  = (i >> 2) & 63;
      int k  = i & 3;
      int u  = w*32 + (l >> 1);
      int hf = l & 1;
      const float* src = whh + ((size_t)(ld*512 + r*128 + u))*HH + 64*hf + jj*8 + 2*k;
      wg[i] = packh2(src[0], src[1]);
    }
  }
}

// ---- x1 (blk<800) | q1 (blk 800..1055) ; reads WXT/WQT written by k_prep ----
__global__ __launch_bounds__(256) void k_xq(const float* __restrict__ x,    const float* __restrict__ bx,
                                            const float* __restrict__ text, const float* __restrict__ bq,
                                            float* __restrict__ ws){
  __shared__ float sbuf[2048];
  int blk = blockIdx.x, tid = threadIdx.x;
  if (blk < 800){
    int b = blk/100; int t0 = (blk%100)*4;
    float (*sx)[4] = (float(*)[4])sbuf;
    for (int i = tid; i < N_MEL*4; i += 256){
      int m = i>>2, ii = i&3;
      sx[m][ii] = x[(b*N_MEL+m)*T_MEL + t0 + ii];
    }
    __syncthreads();
    float bxe = bx[tid];
    float a0=bxe,a1=bxe,a2=bxe,a3=bxe;
    const float* wxt = ws + OFF_WXT;
    #pragma unroll 4
    for (int m=0;m<N_MEL;m++){
      float w = wxt[m*E + tid];
      a0 += sx[m][0]*w; a1 += sx[m][1]*w; a2 += sx[m][2]*w; a3 += sx[m][3]*w;
    }
    float* x1 = ws + OFF_X1 + (b*T_MEL + t0)*E + tid;
    x1[0]=a0; x1[E]=a1; x1[2*E]=a2; x1[3*E]=a3;
  } else {
    int bb = blk - 800;
    int b = bb/32; int l0 = (bb%32)*4;
    float (*st)[D_TXT] = (float(*)[D_TXT])sbuf;
    for (int i = tid; i < 4*D_TXT; i += 256){
      int li = i / D_TXT, k = i % D_TXT;
      st[li][k] = text[(b*L_TXT + l0 + li)*D_TXT + k];
    }
    __syncthreads();
    float bqe = bq[tid];
    float a0=bqe,a1=bqe,a2=bqe,a3=bqe;
    const float* wqt = ws + OFF_WQT;
    #pragma unroll 2
    for (int k=0;k<D_TXT;k++){
      float w = wqt[k*E + tid];
      a0 += st[0][k]*w; a1 += st[1][k]*w; a2 += st[2][k]*w; a3 += st[3][k]*w;
    }
    float* q1 = ws + OFF_Q1 + (b*L_TXT + l0)*E + tid;
    q1[0]=a0; q1[E]=a1; q1[2*E]=a2; q1[3*E]=a3;
  }
}

// ---- scores + masked softmax + context + h0 ; one block per (b,l) ----
__global__ __launch_bounds__(256) void k_score(const int* __restrict__ mel_len,
                                               float* __restrict__ ws,
                                               float* __restrict__ d_out){
  int blk = blockIdx.x; int b = blk >> 7; int l = blk & 127;
  int tid = threadIdx.x; int lane = tid & 63; int wv = tid >> 6;
  __shared__ __align__(16) float sl[T_MEL];
  __shared__ float red[8];
  const float* x1 = ws + OFF_X1 + b*T_MEL*E;
  const float* q1 = ws + OFF_Q1 + (b*L_TXT+l)*E;
  int g = lane >> 4, i = lane & 15;      // group (which t), e-chunk
  float qv[16], wvv[16];
  {
    const float4* q4 = (const float4*)(q1 + i*16);
    const float4* w4 = (const float4*)(ws + OFF_W + i*16);
    #pragma unroll
    for (int j=0;j<4;j++){
      float4 a = q4[j]; qv[4*j]=a.x; qv[4*j+1]=a.y; qv[4*j+2]=a.z; qv[4*j+3]=a.w;
      float4 c = w4[j]; wvv[4*j]=c.x; wvv[4*j+1]=c.y; wvv[4*j+2]=c.z; wvv[4*j+3]=c.w;
    }
  }
  float cc = ws[OFF_C];
  int len = mel_len[b];
  #pragma unroll 2
  for (int iter=0; iter<25; iter++){
    int t = iter*16 + wv*4 + g;
    const float4* xr = (const float4*)(x1 + t*E + i*16);
    float s = 0.f;
    #pragma unroll
    for (int j=0;j<4;j++){
      float4 xv = xr[j];
      s += wvv[4*j+0]*fast_tanh(xv.x + qv[4*j+0]);
      s += wvv[4*j+1]*fast_tanh(xv.y + qv[4*j+1]);
      s += wvv[4*j+2]*fast_tanh(xv.z + qv[4*j+2]);
      s += wvv[4*j+3]*fast_tanh(xv.w + qv[4*j+3]);
    }
    s += __shfl_xor(s,1); s += __shfl_xor(s,2);
    s += __shfl_xor(s,4); s += __shfl_xor(s,8);
    if (i==0) sl[t] = s + cc;
  }
  __syncthreads();
  float mx = -3.0e38f;
  for (int t = tid; t < T_MEL; t += 256) if (t < len) mx = fmaxf(mx, sl[t]);
  #pragma unroll
  for (int off=32; off>=1; off>>=1) mx = fmaxf(mx, __shfl_xor(mx, off));
  if (lane==0) red[wv] = mx;
  __syncthreads();
  mx = fmaxf(fmaxf(red[0],red[1]),fmaxf(red[2],red[3]));
  float se = 0.f;
  for (int t = tid; t < T_MEL; t += 256){
    float p = (t < len) ? __expf(sl[t]-mx) : 0.f;
    sl[t] = p; se += p;
  }
  #pragma unroll
  for (int off=32; off>=1; off>>=1) se += __shfl_xor(se, off);
  if (lane==0) red[4+wv] = se;
  __syncthreads();
  float rsum = 1.f/(red[4]+red[5]+red[6]+red[7]);
  float* sc_out = d_out + 1824 + (b*L_TXT + l)*T_MEL;
  for (int t = tid; t < T_MEL; t += 256){
    float p = sl[t]*rsum;
    sl[t] = p; sc_out[t] = p;
  }
  __syncthreads();
  float a = 0.f;
  int e = tid;
  for (int t = 0; t < T_MEL; t += 4){
    float4 p4 = *(const float4*)&sl[t];     // sl=0 past len -> no guard needed
    a += p4.x*x1[(t  )*E+e] + p4.y*x1[(t+1)*E+e]
       + p4.z*x1[(t+2)*E+e] + p4.w*x1[(t+3)*E+e];
  }
  ws[OFF_H0 + (b*L_TXT+l)*E + e] = q1[e] + a;
}

// ---- gates v2: f16-pair packed inputs + weights, uint4 LDS reads, fdot2 MACs. ----
__global__ __launch_bounds__(512) void k_gates(const float* __restrict__ in,
                                               const float* __restrict__ hs,
                                               const int* __restrict__ txt_len,
                                               float* __restrict__ gates, int layer,
                                               float* __restrict__ ws){
  int idx = blockIdx.x; int tt = idx & 15; int dir = (idx>>4)&1; int b = idx>>5;
  int tid = threadIdx.x;
  __shared__ __align__(16) uint sih[8][128];   // 8 rows x 128 f16-pairs (k = 2*k2)
  int len = txt_len[b];
  for (int i = tid; i < 8*128; i += 512){
    int r = i >> 7, k2 = i & 127;
    int t = tt*8 + r;
    int row = dir ? max(0, len-1-t) : t;
    float va, vb;
    if (layer == 0){
      const float2 p = *(const float2*)&in[((size_t)(b*L_TXT + row))*HID + 2*k2];
      va = p.x; vb = p.y;
    } else {
      int k = 2*k2; int d = k >> 7, u = k & 127;   // k even -> k,k+1 share d
      int sidx = (d==0) ? row : (row < len ? len-1-row : 0);
      const float* hr = hs + (((size_t)(d*8+b)*128) + u)*128 + sidx;
      va = hr[0]; vb = hr[128];
    }
    sih[r][k2] = packh2(va, vb);
  }
  __syncthreads();
  int ld = layer*2 + dir;
  int g = tid;
  float bsum = ws[OFF_BSUM + ld*512 + g];
  float acc[8];
  #pragma unroll
  for (int r=0;r<8;r++) acc[r] = bsum;
  const uint* wt2 = (const uint*)(ws + OFF_WIHT) + (size_t)ld*128*512 + g;
  for (int k4=0; k4<128; k4+=4){
    uint w0 = wt2[(k4  )*512];
    uint w1 = wt2[(k4+1)*512];
    uint w2 = wt2[(k4+2)*512];
    uint w3 = wt2[(k4+3)*512];
    #pragma unroll
    for (int r=0;r<8;r++){
      uint4 s4 = *(const uint4*)&sih[r][k4];
      acc[r] = fdot2(s4.x, w0, acc[r]);
      acc[r] = fdot2(s4.y, w1, acc[r]);
      acc[r] = fdot2(s4.z, w2, acc[r]);
      acc[r] = fdot2(s4.w, w3, acc[r]);
    }
  }
  float* go = gates + (((size_t)(dir*L_TXT + tt*8)*8) + b)*512 + g;
  #pragma unroll
  for (int r=0;r<8;r++) go[(size_t)r*8*512] = acc[r];
}

// ---- recurrent scan v14: v13b with the {g,o} weight half moved to GLOBAL L2 ----
// DS pipe/step: 64 weight-b128 (i,f) + 32 h + 20 shfl = 116 instrs (~1390 cy);
// the 16 global b128/thread for (g,o) stream through the idle VMEM pipe and
// their L2 latency hides under the DS/VALU work (loop-invariant addresses:
// LICM may even hoist them to registers -> free). Math identical to v13b.
__global__ __launch_bounds__(256) void k_scan(const float* __restrict__ Gp,
                                              const float* __restrict__ whh_all,
                                              const uint* __restrict__ wg,
                                              const int* __restrict__ txt_len,
                                              float* __restrict__ hseq,
                                              float* __restrict__ pooled, int layer){
  int dir = blockIdx.x & 1; int b = blockIdx.x >> 1;
  int tid = threadIdx.x;
  int l = tid & 63, w = tid >> 6;   // 4 waves
  int u  = tid >> 1;                // unit 0..127
  int hf = tid & 1;                 // half of h

  __shared__ uint wlds[16384];      // 64KB: gates i,f only ; [w][slot r*8+jj][lane][4]
  __shared__ uint h2buf[2][64];     // rolling h as half2

  const float* wbase = whh_all + (size_t)(layer*2+dir)*512*HH;
  #pragma unroll
  for (int r=0;r<2;r++){
    const float* wr = wbase + (size_t)(r*128+u)*HH + 64*hf;
    #pragma unroll
    for (int jj=0;jj<8;jj++){
      uint4 vv;
      vv.x = packh2(wr[jj*8+0], wr[jj*8+1]);
      vv.y = packh2(wr[jj*8+2], wr[jj*8+3]);
      vv.z = packh2(wr[jj*8+4], wr[jj*8+5]);
      vv.w = packh2(wr[jj*8+6], wr[jj*8+7]);
      *(uint4*)(wlds + w*4096 + (r*8+jj)*256 + l*4) = vv;
    }
  }
  if (tid < 128) ((uint*)h2buf)[tid] = 0;
  int len = txt_len[b];
  bool pool = (layer == 1);

  const float* gb = Gp + ((size_t)(dir*L_TXT)*8 + b)*512 + u;
  float g0 = gb[0], g1 = gb[128], g2 = gb[256], g3 = gb[384];
  float c_reg = 0.f, psum = 0.f;
  float hm1=0.f, hm2=0.f, hm3=0.f;
  __syncthreads();

  const uint4* wp  = (const uint4*)(wlds + w*4096 + l*4);                    // LDS i,f
  const uint*  wgp = wg + (((size_t)(layer*2+dir))*4 + w)*8192 + l*4;       // global g,o
  float* hout = hseq + (((size_t)(dir*8+b)*128) + u)*128;

  for (int s=0; s<L_TXT; s++){
    const float* gn = gb + (size_t)(s+1 < L_TXT ? s+1 : s)*4096;
    float n0 = gn[0], n1 = gn[128], n2 = gn[256], n3 = gn[384];
    const uint4* hp = (const uint4*)(h2buf[s&1] + hf*32);  // 2 addrs/wave: broadcast
    float a0 = hf ? 0.f : g0;
    float a1 = hf ? 0.f : g1;
    float a2 = hf ? 0.f : g2;
    float a3 = hf ? 0.f : g3;
    #pragma unroll
    for (int jj=0;jj<8;jj++){
      uint4 hv = hp[jj];
      uint4 w0 = wp[(jj   )*64];                            // LDS: gate i
      uint4 w1 = wp[( 8+jj)*64];                            // LDS: gate f
      uint4 w2 = *(const uint4*)(wgp + (16+jj)*256);        // L2 : gate g
      uint4 w3 = *(const uint4*)(wgp + (24+jj)*256);        // L2 : gate o
      a0 = fdot2(w0.x,hv.x,a0); a0 = fdot2(w0.y,hv.y,a0);
      a0 = fdot2(w0.z,hv.z,a0); a0 = fdot2(w0.w,hv.w,a0);
      a1 = fdot2(w1.x,hv.x,a1); a1 = fdot2(w1.y,hv.y,a1);
      a1 = fdot2(w1.z,hv.z,a1); a1 = fdot2(w1.w,hv.w,a1);
      a2 = fdot2(w2.x,hv.x,a2); a2 = fdot2(w2.y,hv.y,a2);
      a2 = fdot2(w2.z,hv.z,a2); a2 = fdot2(w2.w,hv.w,a2);
      a3 = fdot2(w3.x,hv.x,a3); a3 = fdot2(w3.y,hv.y,a3);
      a3 = fdot2(w3.z,hv.z,a3); a3 = fdot2(w3.w,hv.w,a3);
    }
    a0 += __shfl_xor(a0, 1);   // join h-halves (tid^1 = same u, other hf)
    a1 += __shfl_xor(a1, 1);
    a2 += __shfl_xor(a2, 1);
    a3 += __shfl_xor(a3, 1);
    float i_ = fast_sigmoid(a0);
    float f_ = fast_sigmoid(a1);
    float g_ = fast_tanh   (a2);
    float o_ = fast_sigmoid(a3);
    c_reg = f_*c_reg + i_*g_;
    float h = o_*fast_tanh(c_reg);
    float hn = __shfl_xor(h, 2);           // unit u^1's h (same hf)
    if (hf==0 && !(u&1)) h2buf[(s+1)&1][u>>1] = packh2(h, hn);
    if (pool){
      if (s < len) psum += h;
    } else {
      if (hf==0 && (s&3)==3)
        *(float4*)&hout[s-3] = make_float4(hm3, hm2, hm1, h);
      hm3 = hm2; hm2 = hm1; hm1 = h;
    }
    g0 = n0; g1 = n1; g2 = n2; g3 = n3;
    __syncthreads();
  }
  if (pool && hf==0) pooled[((size_t)(dir*8+b))*128 + u] = psum;
}

// ---- p1/tanh + normalize + p2 ; pooling read from pooled[] (scan L1 fused it) ----
__global__ __launch_bounds__(256) void k_final(const float* __restrict__ pooled,
                                               const int* __restrict__ txt_len,
                                               const float* __restrict__ p1w,
                                               const float* __restrict__ p1b,
                                               const float* __restrict__ p2w,
                                               const float* __restrict__ p2b,
                                               float* __restrict__ d_out){
  int b = blockIdx.x; int tid = threadIdx.x;
  __shared__ float pl[HID];
  __shared__ float ol[EMB];
  __shared__ float nrm;
  int len = txt_len[b];
  int d = tid >> 7, u = tid & 127;
  pl[tid] = pooled[((size_t)(d*8+b))*128 + u] / (float)len;
  __syncthreads();
  if (tid < EMB){
    float a = p1b[tid];
    for (int k=0;k<HID;k++) a += pl[k]*p1w[tid*HID+k];
    ol[tid] = fast_tanh(a);
  }
  __syncthreads();
  if (tid == 0){
    float q = 0.f;
    for (int k=0;k<EMB;k++) q += ol[k]*ol[k];
    nrm = rsqrtf(q);
  }
  __syncthreads();
  if (tid < EMB) d_out[800 + b*EMB + tid] = ol[tid]*nrm;
  if (tid < N_SPK){
    float a = p2b[tid];
    for (int k=0;k<EMB;k++) a += ol[k]*p2w[tid*EMB+k];
    d_out[b*N_SPK + tid] = a;
  }
}

extern "C" void kernel_launch(void* const* d_in, const int* in_sizes, int n_in,
                              void* d_out, int out_size, void* d_ws, size_t ws_size,
                              hipStream_t stream) {
  const float* x       = (const float*)d_in[0];
  const int*   mel_len = (const int*)  d_in[1];
  const float* text    = (const float*)d_in[2];
  const int*   txt_len = (const int*)  d_in[3];
  const float* Wx      = (const float*)d_in[4];
  const float* bx      = (const float*)d_in[5];
  const float* Wq      = (const float*)d_in[6];
  const float* bq      = (const float*)d_in[7];
  const float* Wout    = (const float*)d_in[8];
  const float* bout    = (const float*)d_in[9];
  const float* v       = (const float*)d_in[10];
  const float* wih     = (const float*)d_in[11];
  const float* whh     = (const float*)d_in[12];
  const float* bih     = (const float*)d_in[13];
  const float* bhh     = (const float*)d_in[14];
  const float* p1w     = (const float*)d_in[15];
  const float* p1b     = (const float*)d_in[16];
  const float* p2w     = (const float*)d_in[17];
  const float* p2b     = (const float*)d_in[18];
  float* ws  = (float*)d_ws;
  float* out = (float*)d_out;
  const uint* wg = (const uint*)(ws + OFF_WG);

  k_prep <<<1122, 256, 0, stream>>>(Wout, bout, v, Wx, Wq, wih, bih, bhh, whh, ws);
  k_xq   <<<1056, 256, 0, stream>>>(x, bx, text, bq, ws);
  k_score<<<1024, 256, 0, stream>>>(mel_len, ws, out);

  float* G = ws + OFF_G;
  k_gates<<<256, 512, 0, stream>>>(ws + OFF_H0, ws + OFF_HS0, txt_len, G, 0, ws);
  k_scan <<<16, 256, 0, stream>>>(G, whh, wg, txt_len, ws + OFF_HS0, ws + OFF_POOL, 0);
  k_gates<<<256, 512, 0, stream>>>(ws + OFF_H0, ws + OFF_HS0, txt_len, G, 1, ws);
  k_scan <<<16, 256, 0, stream>>>(G, whh, wg, txt_len, ws + OFF_HS0, ws + OFF_POOL, 1);

  k_final<<<8, 256, 0, stream>>>(ws + OFF_POOL, txt_len, p1w, p1b, p2w, p2b, out);
}

// Round 18
// 425.814 us; speedup vs baseline: 1.4856x; 1.0084x over previous
//
#include <hip/hip_runtime.h>
#include <hip/hip_bf16.h>
#include <math.h>

#define B 8
#define T_MEL 400
#define N_MEL 80
#define L_TXT 128
#define D_TXT 512
#define E 256
#define HID 256
#define EMB 128
#define N_SPK 100
#define HH 128

// ---- workspace layout (float element offsets) ----
#define OFF_W      0
#define OFF_C      256
#define OFF_WXT    272
#define OFF_WQT    (OFF_WXT + N_MEL*E)        // 20752
#define OFF_WIHT   (OFF_WQT + D_TXT*E)        // 151824 ; uint[4][128][512] f16-pairs (view-cast)
#define OFF_BSUM   (OFF_WIHT + 2*2*256*512)   // 676112
#define OFF_X1     (OFF_BSUM + 2048)          // 678160
#define OFF_Q1     (OFF_X1 + B*T_MEL*E)       // 1497360
#define OFF_G      OFF_X1                      // gates overlay x1+q1 (dead by then)
#define OFF_H0     (OFF_Q1 + B*L_TXT*E)       // 1759504
#define OFF_O1     (OFF_H0 + B*L_TXT*E)       // 2021648
#define OFF_HS0    OFF_H0                      // hseq[2][128][8][128] overlays H0
#define OFF_POOL   OFF_O1                      // pooled[2][8][128] floats (written by scan L1)
#define OFF_WG     (OFF_O1 + 4096)            // uint[4][4][8192] Whh f16-pairs, wave-contig

typedef _Float16 half2v __attribute__((ext_vector_type(2)));

__device__ __forceinline__ float fast_sigmoid(float x){ return 1.f/(1.f+__expf(-x)); }
__device__ __forceinline__ float fast_tanh(float x){ float e=__expf(2.f*x); return 1.f - 2.f/(e+1.f); }

__device__ __forceinline__ float fdot2(uint a, uint b, float c){
  half2v ha = __builtin_bit_cast(half2v, a);
  half2v hb = __builtin_bit_cast(half2v, b);
#if __has_builtin(__builtin_amdgcn_fdot2)
  return __builtin_amdgcn_fdot2(ha, hb, c, false);
#else
  float r;
  asm("v_dot2_f32_f16 %0, %1, %2, %3" : "=v"(r) : "v"(a), "v"(b), "v"(c));
  return r;
#endif
}
__device__ __forceinline__ uint packh2(float a, float b){
  union { _Float16 h[2]; uint u; } x;
  x.h[0] = (_Float16)a; x.h[1] = (_Float16)b; return x.u;
}

// ---- prep v3: tiled LDS transposes (coalesced both sides) ----
// blocks: 0 w/c | 1..4 WXT | 5..36 WQT | 37..68 WIHT | 69 BSUM | 70..85 WG
__global__ __launch_bounds__(256) void k_prep(const float* __restrict__ Wout, const float* __restrict__ bout,
                       const float* __restrict__ v,    const float* __restrict__ Wx,
                       const float* __restrict__ Wq,   const float* __restrict__ wih,
                       const float* __restrict__ bih,  const float* __restrict__ bhh,
                       const float* __restrict__ whh,  float* __restrict__ ws){
  __shared__ __align__(16) float tile[64][81];   // also viewed as uint[64][129] below
  __shared__ __align__(16) uint  utile[64][129];
  int blk = blockIdx.x, tid = threadIdx.x;
  if (blk == 0){
    float acc = 0.f;
    for (int j=0;j<E;j++) acc += Wout[j*E + tid] * v[j];
    ws[OFF_W + tid] = acc;
    if (tid==0){ float c=0.f; for(int j=0;j<E;j++) c += bout[j]*v[j]; ws[OFF_C]=c; }
  } else if (blk <= 4){
    int e0 = (blk-1)*64;
    for (int idx = tid; idx < 64*20; idx += 256){
      int e = idx/20, c4 = idx%20;
      float4 vv = *(const float4*)&Wx[(size_t)(e0+e)*N_MEL + 4*c4];
      tile[e][4*c4]=vv.x; tile[e][4*c4+1]=vv.y; tile[e][4*c4+2]=vv.z; tile[e][4*c4+3]=vv.w;
    }
    __syncthreads();
    for (int idx = tid; idx < N_MEL*64; idx += 256){
      int m = idx>>6, e = idx&63;
      ws[OFF_WXT + m*E + e0 + e] = tile[e][m];
    }
  } else if (blk <= 36){
    int t = blk-5; int e0 = (t&3)*64, k0 = (t>>2)*64;
    for (int idx = tid; idx < 64*16; idx += 256){
      int e = idx>>4, c = idx&15;
      float4 vv = *(const float4*)&Wq[(size_t)(e0+e)*D_TXT + k0 + 4*c];
      tile[e][4*c]=vv.x; tile[e][4*c+1]=vv.y; tile[e][4*c+2]=vv.z; tile[e][4*c+3]=vv.w;
    }
    __syncthreads();
    for (int idx = tid; idx < 64*64; idx += 256){
      int k = idx>>6, e = idx&63;
      ws[OFF_WQT + (k0+k)*E + e0 + e] = tile[e][k];
    }
  } else if (blk <= 68){
    int t = blk-37; int ld = t>>3, g0 = (t&7)*64;
    for (int idx = tid; idx < 64*64; idx += 256){
      int g = idx>>6, c = idx&63;
      float4 vv = *(const float4*)&wih[((size_t)(ld*512+g0+g))*256 + 4*c];
      utile[g][2*c]   = packh2(vv.x, vv.y);
      utile[g][2*c+1] = packh2(vv.z, vv.w);
    }
    __syncthreads();
    uint* wout = (uint*)(ws + OFF_WIHT) + (size_t)ld*128*512;
    for (int idx = tid; idx < 128*64; idx += 256){
      int k2 = idx>>6, g = idx&63;
      wout[(size_t)k2*512 + g0 + g] = utile[g][k2];
    }
  } else if (blk == 69){
    for (int i = tid; i < 2048; i += 256)
      ws[OFF_BSUM + i] = bih[i] + bhh[i];
  } else {
    int bp = blk - 70;              // 0..15
    int ld = bp >> 2, w = bp & 3;
    uint* wg = (uint*)(ws + OFF_WG) + ((size_t)ld*4 + w)*8192;
    for (int ii = 0; ii < 32; ii++){
      int i = ii*256 + tid;         // 0..8191
      int r  = i >> 11;
      int jj = (i >> 8) & 7;
      int l  = (i >> 2) & 63;
      int k  = i & 3;
      int u  = w*32 + (l >> 1);
      int hf = l & 1;
      const float* src = whh + ((size_t)(ld*512 + r*128 + u))*HH + 64*hf + jj*8 + 2*k;
      wg[i] = packh2(src[0], src[1]);
    }
  }
}

// ---- x1 (blk<800) | q1 (blk 800..1055) ; reads WXT/WQT written by k_prep ----
__global__ __launch_bounds__(256) void k_xq(const float* __restrict__ x,    const float* __restrict__ bx,
                                            const float* __restrict__ text, const float* __restrict__ bq,
                                            float* __restrict__ ws){
  __shared__ float sbuf[2048];
  int blk = blockIdx.x, tid = threadIdx.x;
  if (blk < 800){
    int b = blk/100; int t0 = (blk%100)*4;
    float (*sx)[4] = (float(*)[4])sbuf;
    for (int i = tid; i < N_MEL*4; i += 256){
      int m = i>>2, ii = i&3;
      sx[m][ii] = x[(b*N_MEL+m)*T_MEL + t0 + ii];
    }
    __syncthreads();
    float bxe = bx[tid];
    float a0=bxe,a1=bxe,a2=bxe,a3=bxe;
    const float* wxt = ws + OFF_WXT;
    #pragma unroll 4
    for (int m=0;m<N_MEL;m++){
      float w = wxt[m*E + tid];
      a0 += sx[m][0]*w; a1 += sx[m][1]*w; a2 += sx[m][2]*w; a3 += sx[m][3]*w;
    }
    float* x1 = ws + OFF_X1 + (b*T_MEL + t0)*E + tid;
    x1[0]=a0; x1[E]=a1; x1[2*E]=a2; x1[3*E]=a3;
  } else {
    int bb = blk - 800;
    int b = bb/32; int l0 = (bb%32)*4;
    float (*st)[D_TXT] = (float(*)[D_TXT])sbuf;
    for (int i = tid; i < 4*D_TXT; i += 256){
      int li = i / D_TXT, k = i % D_TXT;
      st[li][k] = text[(b*L_TXT + l0 + li)*D_TXT + k];
    }
    __syncthreads();
    float bqe = bq[tid];
    float a0=bqe,a1=bqe,a2=bqe,a3=bqe;
    const float* wqt = ws + OFF_WQT;
    #pragma unroll 2
    for (int k=0;k<D_TXT;k++){
      float w = wqt[k*E + tid];
      a0 += st[0][k]*w; a1 += st[1][k]*w; a2 += st[2][k]*w; a3 += st[3][k]*w;
    }
    float* q1 = ws + OFF_Q1 + (b*L_TXT + l0)*E + tid;
    q1[0]=a0; q1[E]=a1; q1[2*E]=a2; q1[3*E]=a3;
  }
}

// ---- scores + masked softmax + context + h0 ; one block per (b,l) ----
__global__ __launch_bounds__(256) void k_score(const int* __restrict__ mel_len,
                                               float* __restrict__ ws,
                                               float* __restrict__ d_out){
  int blk = blockIdx.x; int b = blk >> 7; int l = blk & 127;
  int tid = threadIdx.x; int lane = tid & 63; int wv = tid >> 6;
  __shared__ __align__(16) float sl[T_MEL];
  __shared__ float red[8];
  const float* x1 = ws + OFF_X1 + b*T_MEL*E;
  const float* q1 = ws + OFF_Q1 + (b*L_TXT+l)*E;
  int g = lane >> 4, i = lane & 15;      // group (which t), e-chunk
  float qv[16], wvv[16];
  {
    const float4* q4 = (const float4*)(q1 + i*16);
    const float4* w4 = (const float4*)(ws + OFF_W + i*16);
    #pragma unroll
    for (int j=0;j<4;j++){
      float4 a = q4[j]; qv[4*j]=a.x; qv[4*j+1]=a.y; qv[4*j+2]=a.z; qv[4*j+3]=a.w;
      float4 c = w4[j]; wvv[4*j]=c.x; wvv[4*j+1]=c.y; wvv[4*j+2]=c.z; wvv[4*j+3]=c.w;
    }
  }
  float cc = ws[OFF_C];
  int len = mel_len[b];
  #pragma unroll 2
  for (int iter=0; iter<25; iter++){
    int t = iter*16 + wv*4 + g;
    const float4* xr = (const float4*)(x1 + t*E + i*16);
    float s = 0.f;
    #pragma unroll
    for (int j=0;j<4;j++){
      float4 xv = xr[j];
      s += wvv[4*j+0]*fast_tanh(xv.x + qv[4*j+0]);
      s += wvv[4*j+1]*fast_tanh(xv.y + qv[4*j+1]);
      s += wvv[4*j+2]*fast_tanh(xv.z + qv[4*j+2]);
      s += wvv[4*j+3]*fast_tanh(xv.w + qv[4*j+3]);
    }
    s += __shfl_xor(s,1); s += __shfl_xor(s,2);
    s += __shfl_xor(s,4); s += __shfl_xor(s,8);
    if (i==0) sl[t] = s + cc;
  }
  __syncthreads();
  float mx = -3.0e38f;
  for (int t = tid; t < T_MEL; t += 256) if (t < len) mx = fmaxf(mx, sl[t]);
  #pragma unroll
  for (int off=32; off>=1; off>>=1) mx = fmaxf(mx, __shfl_xor(mx, off));
  if (lane==0) red[wv] = mx;
  __syncthreads();
  mx = fmaxf(fmaxf(red[0],red[1]),fmaxf(red[2],red[3]));
  float se = 0.f;
  for (int t = tid; t < T_MEL; t += 256){
    float p = (t < len) ? __expf(sl[t]-mx) : 0.f;
    sl[t] = p; se += p;
  }
  #pragma unroll
  for (int off=32; off>=1; off>>=1) se += __shfl_xor(se, off);
  if (lane==0) red[4+wv] = se;
  __syncthreads();
  float rsum = 1.f/(red[4]+red[5]+red[6]+red[7]);
  float* sc_out = d_out + 1824 + (b*L_TXT + l)*T_MEL;
  for (int t = tid; t < T_MEL; t += 256){
    float p = sl[t]*rsum;
    sl[t] = p; sc_out[t] = p;
  }
  __syncthreads();
  float a = 0.f;
  int e = tid;
  for (int t = 0; t < T_MEL; t += 4){
    float4 p4 = *(const float4*)&sl[t];     // sl=0 past len -> no guard needed
    a += p4.x*x1[(t  )*E+e] + p4.y*x1[(t+1)*E+e]
       + p4.z*x1[(t+2)*E+e] + p4.w*x1[(t+3)*E+e];
  }
  ws[OFF_H0 + (b*L_TXT+l)*E + e] = q1[e] + a;
}

// ---- gates v3: layer0 reads H0[b][l][256]; layer1 reads hseq[d][s][b][u]
//      (contiguous float2, fully coalesced). output: G[dir][t][b][row]. ----
__global__ __launch_bounds__(512) void k_gates(const float* __restrict__ in,
                                               const float* __restrict__ hs,
                                               const int* __restrict__ txt_len,
                                               float* __restrict__ gates, int layer,
                                               float* __restrict__ ws){
  int idx = blockIdx.x; int tt = idx & 15; int dir = (idx>>4)&1; int b = idx>>5;
  int tid = threadIdx.x;
  __shared__ __align__(16) uint sih[8][128];   // 8 rows x 128 f16-pairs (k = 2*k2)
  int len = txt_len[b];
  for (int i = tid; i < 8*128; i += 512){
    int r = i >> 7, k2 = i & 127;
    int t = tt*8 + r;
    int row = dir ? max(0, len-1-t) : t;
    float va, vb;
    if (layer == 0){
      const float2 p = *(const float2*)&in[((size_t)(b*L_TXT + row))*HID + 2*k2];
      va = p.x; vb = p.y;
    } else {
      int k = 2*k2; int d = k >> 7, u = k & 127;   // k even -> k,k+1 share d
      int sidx = (d==0) ? row : (row < len ? len-1-row : 0);
      const float2 p = *(const float2*)&hs[(((size_t)d*L_TXT + sidx)*8 + b)*128 + u];
      va = p.x; vb = p.y;
    }
    sih[r][k2] = packh2(va, vb);
  }
  __syncthreads();
  int ld = layer*2 + dir;
  int g = tid;
  float bsum = ws[OFF_BSUM + ld*512 + g];
  float acc[8];
  #pragma unroll
  for (int r=0;r<8;r++) acc[r] = bsum;
  const uint* wt2 = (const uint*)(ws + OFF_WIHT) + (size_t)ld*128*512 + g;
  for (int k4=0; k4<128; k4+=4){
    uint w0 = wt2[(k4  )*512];
    uint w1 = wt2[(k4+1)*512];
    uint w2 = wt2[(k4+2)*512];
    uint w3 = wt2[(k4+3)*512];
    #pragma unroll
    for (int r=0;r<8;r++){
      uint4 s4 = *(const uint4*)&sih[r][k4];
      acc[r] = fdot2(s4.x, w0, acc[r]);
      acc[r] = fdot2(s4.y, w1, acc[r]);
      acc[r] = fdot2(s4.z, w2, acc[r]);
      acc[r] = fdot2(s4.w, w3, acc[r]);
    }
  }
  float* go = gates + (((size_t)(dir*L_TXT + tt*8)*8) + b)*512 + g;
  #pragma unroll
  for (int r=0;r<8;r++) go[(size_t)r*8*512] = acc[r];
}

// ---- recurrent scan v15: v14 + {g,o} weights HOISTED to registers.
// LDS padded to ~96KB -> 1 block/CU -> allocator grants VGPRs (R16 evidence:
// 1blk/CU gave 132 freely; 2blk/CU capped at 88). 16 loop-invariant uint4
// pinned in regs kills the per-step VMEM latency. DS/step: 64 wgt + 32 h +
// 20 shfl = 116 instrs (~1390cy). hseq layout [dir][s][b][u]: coalesced store.
__global__ __launch_bounds__(256) void k_scan(const float* __restrict__ Gp,
                                              const float* __restrict__ whh_all,
                                              const uint* __restrict__ wg,
                                              const int* __restrict__ txt_len,
                                              float* __restrict__ hseq,
                                              float* __restrict__ pooled, int layer){
  int dir = blockIdx.x & 1; int b = blockIdx.x >> 1;
  int tid = threadIdx.x;
  int l = tid & 63, w = tid >> 6;   // 4 waves
  int u  = tid >> 1;                // unit 0..127
  int hf = tid & 1;                 // half of h

  __shared__ uint wlds[24576];      // 96KB declared (64KB used) -> forces 1 block/CU
  __shared__ uint h2buf[2][64];     // rolling h as half2

  const float* wbase = whh_all + (size_t)(layer*2+dir)*512*HH;
  #pragma unroll
  for (int r=0;r<2;r++){
    const float* wr = wbase + (size_t)(r*128+u)*HH + 64*hf;
    #pragma unroll
    for (int jj=0;jj<8;jj++){
      uint4 vv;
      vv.x = packh2(wr[jj*8+0], wr[jj*8+1]);
      vv.y = packh2(wr[jj*8+2], wr[jj*8+3]);
      vv.z = packh2(wr[jj*8+4], wr[jj*8+5]);
      vv.w = packh2(wr[jj*8+6], wr[jj*8+7]);
      *(uint4*)(wlds + w*4096 + (r*8+jj)*256 + l*4) = vv;
    }
  }
  if (tid < 128) ((uint*)h2buf)[tid] = 0;
  int len = txt_len[b];
  bool pool = (layer == 1);

  // hoist loop-invariant {g,o} weights into registers (16 uint4 = 64 VGPR)
  const uint* wgp = wg + (((size_t)(layer*2+dir))*4 + w)*8192 + l*4;
  uint4 wg2[8], wg3[8];
  #pragma unroll
  for (int jj=0;jj<8;jj++){
    wg2[jj] = *(const uint4*)(wgp + (16+jj)*256);
    wg3[jj] = *(const uint4*)(wgp + (24+jj)*256);
  }
  #pragma unroll
  for (int jj=0;jj<8;jj++){
    asm volatile("" : "+v"(wg2[jj].x), "+v"(wg2[jj].y), "+v"(wg2[jj].z), "+v"(wg2[jj].w));
    asm volatile("" : "+v"(wg3[jj].x), "+v"(wg3[jj].y), "+v"(wg3[jj].z), "+v"(wg3[jj].w));
  }

  const float* gb = Gp + ((size_t)(dir*L_TXT)*8 + b)*512 + u;
  float g0 = gb[0], g1 = gb[128], g2 = gb[256], g3 = gb[384];
  float c_reg = 0.f, psum = 0.f;
  __syncthreads();

  const uint4* wp = (const uint4*)(wlds + w*4096 + l*4);   // LDS i,f ; slot j at wp[j*64]

  for (int s=0; s<L_TXT; s++){
    const float* gn = gb + (size_t)(s+1 < L_TXT ? s+1 : s)*4096;
    float n0 = gn[0], n1 = gn[128], n2 = gn[256], n3 = gn[384];
    const uint4* hp = (const uint4*)(h2buf[s&1] + hf*32);  // 2 addrs/wave: broadcast
    float a0 = hf ? 0.f : g0;
    float a1 = hf ? 0.f : g1;
    float a2 = hf ? 0.f : g2;
    float a3 = hf ? 0.f : g3;
    #pragma unroll
    for (int jj=0;jj<8;jj++){
      uint4 hv = hp[jj];
      uint4 w0 = wp[(jj   )*64];                            // LDS: gate i
      uint4 w1 = wp[( 8+jj)*64];                            // LDS: gate f
      uint4 w2 = wg2[jj];                                   // REG: gate g
      uint4 w3 = wg3[jj];                                   // REG: gate o
      a0 = fdot2(w0.x,hv.x,a0); a0 = fdot2(w0.y,hv.y,a0);
      a0 = fdot2(w0.z,hv.z,a0); a0 = fdot2(w0.w,hv.w,a0);
      a1 = fdot2(w1.x,hv.x,a1); a1 = fdot2(w1.y,hv.y,a1);
      a1 = fdot2(w1.z,hv.z,a1); a1 = fdot2(w1.w,hv.w,a1);
      a2 = fdot2(w2.x,hv.x,a2); a2 = fdot2(w2.y,hv.y,a2);
      a2 = fdot2(w2.z,hv.z,a2); a2 = fdot2(w2.w,hv.w,a2);
      a3 = fdot2(w3.x,hv.x,a3); a3 = fdot2(w3.y,hv.y,a3);
      a3 = fdot2(w3.z,hv.z,a3); a3 = fdot2(w3.w,hv.w,a3);
    }
    a0 += __shfl_xor(a0, 1);   // join h-halves (tid^1 = same u, other hf)
    a1 += __shfl_xor(a1, 1);
    a2 += __shfl_xor(a2, 1);
    a3 += __shfl_xor(a3, 1);
    float i_ = fast_sigmoid(a0);
    float f_ = fast_sigmoid(a1);
    float g_ = fast_tanh   (a2);
    float o_ = fast_sigmoid(a3);
    c_reg = f_*c_reg + i_*g_;
    float h = o_*fast_tanh(c_reg);
    float hn = __shfl_xor(h, 2);           // unit u^1's h (same hf)
    if (hf==0 && !(u&1)) h2buf[(s+1)&1][u>>1] = packh2(h, hn);
    if (pool){
      if (s < len) psum += h;
    } else {
      if (hf==0) hseq[(((size_t)dir*L_TXT + s)*8 + b)*128 + u] = h;  // coalesced
    }
    g0 = n0; g1 = n1; g2 = n2; g3 = n3;
    __syncthreads();
  }
  if (pool && hf==0) pooled[((size_t)(dir*8+b))*128 + u] = psum;
}

// ---- p1/tanh + normalize + p2 ; pooling read from pooled[] (scan L1 fused it) ----
__global__ __launch_bounds__(256) void k_final(const float* __restrict__ pooled,
                                               const int* __restrict__ txt_len,
                                               const float* __restrict__ p1w,
                                               const float* __restrict__ p1b,
                                               const float* __restrict__ p2w,
                                               const float* __restrict__ p2b,
                                               float* __restrict__ d_out){
  int b = blockIdx.x; int tid = threadIdx.x;
  __shared__ float pl[HID];
  __shared__ float ol[EMB];
  __shared__ float nrm;
  int len = txt_len[b];
  int d = tid >> 7, u = tid & 127;
  pl[tid] = pooled[((size_t)(d*8+b))*128 + u] / (float)len;
  __syncthreads();
  if (tid < EMB){
    float a = p1b[tid];
    for (int k=0;k<HID;k++) a += pl[k]*p1w[tid*HID+k];
    ol[tid] = fast_tanh(a);
  }
  __syncthreads();
  if (tid == 0){
    float q = 0.f;
    for (int k=0;k<EMB;k++) q += ol[k]*ol[k];
    nrm = rsqrtf(q);
  }
  __syncthreads();
  if (tid < EMB) d_out[800 + b*EMB + tid] = ol[tid]*nrm;
  if (tid < N_SPK){
    float a = p2b[tid];
    for (int k=0;k<EMB;k++) a += ol[k]*p2w[tid*EMB+k];
    d_out[b*N_SPK + tid] = a;
  }
}

extern "C" void kernel_launch(void* const* d_in, const int* in_sizes, int n_in,
                              void* d_out, int out_size, void* d_ws, size_t ws_size,
                              hipStream_t stream) {
  const float* x       = (const float*)d_in[0];
  const int*   mel_len = (const int*)  d_in[1];
  const float* text    = (const float*)d_in[2];
  const int*   txt_len = (const int*)  d_in[3];
  const float* Wx      = (const float*)d_in[4];
  const float* bx      = (const float*)d_in[5];
  const float* Wq      = (const float*)d_in[6];
  const float* bq      = (const float*)d_in[7];
  const float* Wout    = (const float*)d_in[8];
  const float* bout    = (const float*)d_in[9];
  const float* v       = (const float*)d_in[10];
  const float* wih     = (const float*)d_in[11];
  const float* whh     = (const float*)d_in[12];
  const float* bih     = (const float*)d_in[13];
  const float* bhh     = (const float*)d_in[14];
  const float* p1w     = (const float*)d_in[15];
  const float* p1b     = (const float*)d_in[16];
  const float* p2w     = (const float*)d_in[17];
  const float* p2b     = (const float*)d_in[18];
  float* ws  = (float*)d_ws;
  float* out = (float*)d_out;
  const uint* wg = (const uint*)(ws + OFF_WG);

  k_prep <<<86, 256, 0, stream>>>(Wout, bout, v, Wx, Wq, wih, bih, bhh, whh, ws);
  k_xq   <<<1056, 256, 0, stream>>>(x, bx, text, bq, ws);
  k_score<<<1024, 256, 0, stream>>>(mel_len, ws, out);

  float* G = ws + OFF_G;
  k_gates<<<256, 512, 0, stream>>>(ws + OFF_H0, ws + OFF_HS0, txt_len, G, 0, ws);
  k_scan <<<16, 256, 0, stream>>>(G, whh, wg, txt_len, ws + OFF_HS0, ws + OFF_POOL, 0);
  k_gates<<<256, 512, 0, stream>>>(ws + OFF_H0, ws + OFF_HS0, txt_len, G, 1, ws);
  k_scan <<<16, 256, 0, stream>>>(G, whh, wg, txt_len, ws + OFF_HS0, ws + OFF_POOL, 1);

  k_final<<<8, 256, 0, stream>>>(ws + OFF_POOL, txt_len, p1w, p1b, p2w, p2b, out);
}